// Round 11
// baseline (511.362 us; speedup 1.0000x reference)
//
#include <hip/hip_runtime.h>
#include <hip/hip_bf16.h>
#include <math.h>

#define BB 8
#define NN 2048
#define KK 20

typedef short bf16x8 __attribute__((ext_vector_type(8)));
typedef float f32x4 __attribute__((ext_vector_type(4)));

// fp32 -> bf16 (round-to-nearest-even), finite inputs only
__device__ __forceinline__ unsigned short f2bf(float f) {
  unsigned u = __float_as_uint(f);
  u += 0x7FFFu + ((u >> 16) & 1u);
  return (unsigned short)(u >> 16);
}
__device__ __forceinline__ float bf2f(unsigned short h) {
  return __uint_as_float(((unsigned)h) << 16);
}

// ---------------------------------------------------------------------------
// top-K (K=20) smallest-value tracker (divergent; used by merge only).
// ---------------------------------------------------------------------------
__device__ __forceinline__ void topk_insert(float d, int m, float (&bd)[KK], int (&bi)[KK],
                                            float& worst, int& wslot) {
  if (d < worst) {
#pragma unroll
    for (int j = 0; j < KK; ++j) {
      if (j == wslot) { bd[j] = d; bi[j] = m; }
    }
    float w = -INFINITY;
    int s = 0;
#pragma unroll
    for (int j = 0; j < KK; ++j) {
      if (bd[j] > w) { w = bd[j]; s = j; }
    }
    worst = w;
    wslot = s;
  }
}

// ---------------------------------------------------------------------------
// Branch-free sorted top-20 VALUE list (descending; s[0] = current 20th
// smallest). Insert = min/max chain, self-filtering.
// ---------------------------------------------------------------------------
__device__ __forceinline__ void sins20(float (&s)[KK], float d) {
#pragma unroll
  for (int q = 0; q < KK - 1; ++q) s[q] = fminf(s[q], fmaxf(s[q + 1], d));
  s[KK - 1] = fminf(s[KK - 1], d);
}

// knn1 distance: explicit fmaf composition -> bit-identical across passes.
__device__ __forceinline__ float knn1_dist(float sn, float ssq,
                                           float x0, float x1, float x2,
                                           float y0, float y1, float y2) {
  const float dot = fmaf(x0, y0, fmaf(x1, y1, x2 * y2));
  return fmaf(-2.f, dot, sn + ssq);
}

// ---------------------------------------------------------------------------
// kNN pass 1 for conv1 (D=3), m-chunked; 3-pass tau selection (proven R9).
// ---------------------------------------------------------------------------
__global__ __launch_bounds__(256) void knn1_part(const float* __restrict__ pos,
                                                 float* __restrict__ candd,
                                                 int* __restrict__ candi) {
  __shared__ float xs0[256], xs1[256], xs2[256], ss[256];
  const int bid = blockIdx.x;
  const int b = bid >> 6;
  const int nc = (bid >> 3) & 7;
  const int mc = bid & 7;
  const int t = threadIdx.x;
  const float* posb = pos + (size_t)b * NN * 3;
  {
    const int m = mc * 256 + t;
    const float a0 = posb[m * 3 + 0];
    const float a1 = posb[m * 3 + 1];
    const float a2 = posb[m * 3 + 2];
    xs0[t] = a0; xs1[t] = a1; xs2[t] = a2;
    ss[t] = a0 * a0 + a1 * a1 + a2 * a2;
  }
  __syncthreads();
  const int n = nc * 256 + t;
  const float xn0 = posb[n * 3 + 0];
  const float xn1 = posb[n * 3 + 1];
  const float xn2 = posb[n * 3 + 2];
  const float sn = xn0 * xn0 + xn1 * xn1 + xn2 * xn2;

  float s[KK];
#pragma unroll
  for (int q = 0; q < KK; ++q) s[q] = INFINITY;
  for (int lm = 0; lm < 256; lm += 8) {
    float dv[8];
#pragma unroll
    for (int u = 0; u < 8; ++u)
      dv[u] = knn1_dist(sn, ss[lm + u], xn0, xn1, xn2, xs0[lm + u], xs1[lm + u], xs2[lm + u]);
#pragma unroll
    for (int u = 0; u < 8; ++u) sins20(s, dv[u]);
  }
  const float tau = s[0];

  int cA = 0;
  for (int lm = 0; lm < 256; lm += 8) {
#pragma unroll
    for (int u = 0; u < 8; ++u) {
      const float d = knn1_dist(sn, ss[lm + u], xn0, xn1, xn2, xs0[lm + u], xs1[lm + u], xs2[lm + u]);
      cA += (d < tau) ? 1 : 0;
    }
  }

  int posA = 0, posB = cA;   // cA <= 19 by definition of tau
  const int rbase = mc * 256;
  const size_t obase = ((size_t)(b * 8 + mc) * KK) * 2048 + n;
  for (int lm = 0; lm < 256; lm += 8) {
#pragma unroll
    for (int u = 0; u < 8; ++u) {
      const float d = knn1_dist(sn, ss[lm + u], xn0, xn1, xn2, xs0[lm + u], xs1[lm + u], xs2[lm + u]);
      if (d < tau) {
        candd[obase + (size_t)posA * 2048] = d;
        candi[obase + (size_t)posA * 2048] = rbase + lm + u;
        ++posA;
      } else if (d == tau && posB < KK) {
        candd[obase + (size_t)posB * 2048] = d;
        candi[obase + (size_t)posB * 2048] = rbase + lm + u;
        ++posB;
      }
    }
  }
}

// ---------------------------------------------------------------------------
// merge v2 (unchanged, proven).
// ---------------------------------------------------------------------------
template <int NCH, int G>
__global__ __launch_bounds__(256) void merge_topk2(const float* __restrict__ candd,
                                                   const int* __restrict__ candi,
                                                   int* __restrict__ idx_out) {
  const int gid = blockIdx.x * 256 + threadIdx.x;
  const int pt = gid / G;
  const int sub = gid % G;
  const int b = pt >> 11, n = pt & 2047;
  constexpr int CPT = NCH / G;
  float bd[KK]; int bi[KK];
#pragma unroll
  for (int j = 0; j < KK; ++j) { bd[j] = INFINITY; bi[j] = 0; }
  float worst = INFINITY;
  int wslot = 0;
#pragma unroll
  for (int cc = 0; cc < CPT; ++cc) {
    const int c = sub * CPT + cc;
    const size_t base = ((size_t)(b * NCH + c) * KK) * 2048 + n;
    float dv[KK]; int iv[KK];
#pragma unroll
    for (int j = 0; j < KK; ++j) dv[j] = candd[base + (size_t)j * 2048];
#pragma unroll
    for (int j = 0; j < KK; ++j) iv[j] = candi[base + (size_t)j * 2048];
#pragma unroll
    for (int j = 0; j < KK; ++j) topk_insert(dv[j], iv[j], bd, bi, worst, wslot);
  }
#pragma unroll
  for (int stride = 1; stride < G; stride <<= 1) {
    float od[KK]; int oi[KK];
#pragma unroll
    for (int q = 0; q < KK; ++q) {
      od[q] = __shfl_xor(bd[q], stride);
      oi[q] = __shfl_xor(bi[q], stride);
    }
#pragma unroll
    for (int q = 0; q < KK; ++q) topk_insert(od[q], oi[q], bd, bi, worst, wslot);
  }
  if (sub == 0) {
    int* op = idx_out + (size_t)pt * KK;
#pragma unroll
    for (int j = 0; j < KK; ++j) op[j] = bi[j];
  }
}

// ---------------------------------------------------------------------------
// pre1: per-point factorized conv1 layer-1.
// ---------------------------------------------------------------------------
__global__ __launch_bounds__(256) void pre1_kernel(const float* __restrict__ pos,
                                                   const float* __restrict__ w1,
                                                   const float* __restrict__ b1,
                                                   float* __restrict__ U1,
                                                   float* __restrict__ V1) {
  const int t = threadIdx.x;
  const int c = t & 63;
  const int n = blockIdx.x * 4 + (t >> 6);
  const float p0 = pos[(size_t)n * 3 + 0];
  const float p1 = pos[(size_t)n * 3 + 1];
  const float p2 = pos[(size_t)n * 3 + 2];
  const float wt0 = w1[0 * 64 + c], wt1 = w1[1 * 64 + c], wt2 = w1[2 * 64 + c];
  const float wb0 = w1[3 * 64 + c], wb1 = w1[4 * 64 + c], wb2 = w1[5 * 64 + c];
  float v = p0 * wb0 + p1 * wb1 + p2 * wb2;
  float u = p0 * (wt0 - wb0) + p1 * (wt1 - wb1) + p2 * (wt2 - wb2) + b1[c];
  U1[(size_t)n * 64 + c] = u;
  V1[(size_t)n * 64 + c] = v;
}

// ---------------------------------------------------------------------------
// pre2: per-point factorized conv2 layer-1 (unchanged).
// ---------------------------------------------------------------------------
__global__ __launch_bounds__(256) void pre2_kernel(const float* __restrict__ x1,
                                                   const float* __restrict__ w1,
                                                   const float* __restrict__ b1,
                                                   float* __restrict__ U,
                                                   float* __restrict__ V) {
  __shared__ float X[64][68];
  const int nbase = blockIdx.x * 64;
  const int t = threadIdx.x;
  for (int it = t; it < 1024; it += 256) {
    const int r = it >> 4, q = it & 15;
    *(float4*)&X[r][q * 4] = *(const float4*)&x1[(size_t)(nbase + r) * 64 + q * 4];
  }
  __syncthreads();
  const int ty = t >> 4, tx = t & 15;
  const int c0 = tx * 8;
  float accT[4][8], accB[4][8];
#pragma unroll
  for (int u = 0; u < 4; ++u)
#pragma unroll
    for (int i = 0; i < 8; ++i) { accT[u][i] = 0.f; accB[u][i] = 0.f; }
  for (int d0 = 0; d0 < 64; d0 += 4) {
    float4 a[4];
#pragma unroll
    for (int u = 0; u < 4; ++u) a[u] = *(const float4*)&X[ty * 4 + u][d0];
#pragma unroll
    for (int dd = 0; dd < 4; ++dd) {
      const float4 t0 = *(const float4*)&w1[(size_t)(d0 + dd) * 128 + c0];
      const float4 t1 = *(const float4*)&w1[(size_t)(d0 + dd) * 128 + c0 + 4];
      const float4 bb0 = *(const float4*)&w1[(size_t)(64 + d0 + dd) * 128 + c0];
      const float4 bb1 = *(const float4*)&w1[(size_t)(64 + d0 + dd) * 128 + c0 + 4];
#pragma unroll
      for (int u = 0; u < 4; ++u) {
        const float av = (dd == 0) ? a[u].x : (dd == 1) ? a[u].y : (dd == 2) ? a[u].z : a[u].w;
        accT[u][0] = fmaf(av, t0.x, accT[u][0]);
        accT[u][1] = fmaf(av, t0.y, accT[u][1]);
        accT[u][2] = fmaf(av, t0.z, accT[u][2]);
        accT[u][3] = fmaf(av, t0.w, accT[u][3]);
        accT[u][4] = fmaf(av, t1.x, accT[u][4]);
        accT[u][5] = fmaf(av, t1.y, accT[u][5]);
        accT[u][6] = fmaf(av, t1.z, accT[u][6]);
        accT[u][7] = fmaf(av, t1.w, accT[u][7]);
        accB[u][0] = fmaf(av, bb0.x, accB[u][0]);
        accB[u][1] = fmaf(av, bb0.y, accB[u][1]);
        accB[u][2] = fmaf(av, bb0.z, accB[u][2]);
        accB[u][3] = fmaf(av, bb0.w, accB[u][3]);
        accB[u][4] = fmaf(av, bb1.x, accB[u][4]);
        accB[u][5] = fmaf(av, bb1.y, accB[u][5]);
        accB[u][6] = fmaf(av, bb1.z, accB[u][6]);
        accB[u][7] = fmaf(av, bb1.w, accB[u][7]);
      }
    }
  }
  const float4 bA = *(const float4*)&b1[c0];
  const float4 bB = *(const float4*)&b1[c0 + 4];
#pragma unroll
  for (int u = 0; u < 4; ++u) {
    const size_t row = (size_t)(nbase + ty * 4 + u) * 128 + c0;
    float4 u0, u1, v0, v1;
    v0 = make_float4(accB[u][0], accB[u][1], accB[u][2], accB[u][3]);
    v1 = make_float4(accB[u][4], accB[u][5], accB[u][6], accB[u][7]);
    u0.x = accT[u][0] - accB[u][0] + bA.x;
    u0.y = accT[u][1] - accB[u][1] + bA.y;
    u0.z = accT[u][2] - accB[u][2] + bA.z;
    u0.w = accT[u][3] - accB[u][3] + bA.w;
    u1.x = accT[u][4] - accB[u][4] + bB.x;
    u1.y = accT[u][5] - accB[u][5] + bB.y;
    u1.z = accT[u][6] - accB[u][6] + bB.z;
    u1.w = accT[u][7] - accB[u][7] + bB.w;
    *(float4*)&U[row] = u0;
    *(float4*)&U[row + 4] = u1;
    *(float4*)&V[row] = v0;
    *(float4*)&V[row + 4] = v1;
  }
}

// ---------------------------------------------------------------------------
// wprep: transpose+convert weights for MFMA B-fragments.
// ---------------------------------------------------------------------------
__global__ __launch_bounds__(256) void wprep_kernel(
    const float* __restrict__ c2w2, const float* __restrict__ c2w3,
    const float* __restrict__ c1w2, const float* __restrict__ c1w3,
    const float* __restrict__ l0w,
    unsigned short* __restrict__ w2t, unsigned short* __restrict__ w3t,
    unsigned short* __restrict__ c1w2hi, unsigned short* __restrict__ c1w2lo,
    unsigned short* __restrict__ c1w3hi, unsigned short* __restrict__ c1w3lo,
    unsigned short* __restrict__ l0thi, unsigned short* __restrict__ l0tlo) {
  const int i = blockIdx.x * 256 + threadIdx.x;
  if (i < 16384) {
    const int d = i >> 7, c = i & 127;
    w2t[c * 128 + d] = f2bf(c2w2[i]);
  } else if (i < 49152) {
    const int j = i - 16384;
    const int d = j >> 8, c = j & 255;
    w3t[c * 128 + d] = f2bf(c2w3[j]);
  } else if (i < 53248) {
    const int j = i - 49152;
    const int d = j >> 6, c = j & 63;
    const float v = c1w2[j];
    const unsigned short h = f2bf(v);
    c1w2hi[c * 64 + d] = h;
    c1w2lo[c * 64 + d] = f2bf(v - bf2f(h));
  } else if (i < 57344) {
    const int j = i - 53248;
    const int d = j >> 6, c = j & 63;
    const float v = c1w3[j];
    const unsigned short h = f2bf(v);
    c1w3hi[c * 64 + d] = h;
    c1w3lo[c * 64 + d] = f2bf(v - bf2f(h));
  } else if (i < 188416) {
    const int j = i - 57344;             // < 131072 = 256*512
    const int d = j >> 9, c = j & 511;
    const float v = l0w[j];
    const unsigned short h = f2bf(v);
    l0thi[c * 256 + d] = h;
    l0tlo[c * 256 + d] = f2bf(v - bf2f(h));
  }
}

// ---------------------------------------------------------------------------
// conv1 EdgeConv layers 2,3 via SPLIT-bf16 MFMA (unchanged, proven).
// ---------------------------------------------------------------------------
__global__ __launch_bounds__(256) void conv1_kernel(
    const float* __restrict__ U1, const float* __restrict__ V1,
    const int* __restrict__ idx,
    const unsigned short* __restrict__ w2hi, const unsigned short* __restrict__ w2lo,
    const float* __restrict__ b2,
    const unsigned short* __restrict__ w3hi, const unsigned short* __restrict__ w3lo,
    const float* __restrict__ b3,
    float* __restrict__ xout) {
  __shared__ __align__(16) unsigned short A[160][2][76];
  __shared__ unsigned int pm[8][64];
  const int bid = blockIdx.x;
  const int b = bid >> 8;
  const int pbase = (bid & 255) * 8;
  const int t = threadIdx.x;
  const int wave = t >> 6, lane = t & 63;
  const int lrow = lane & 15;
  const int lk8 = (lane >> 4) * 8;
  const int c = wave * 16 + lrow;

  for (int it = t; it < 2560; it += 256) {
    const int r = it >> 4, q = it & 15;
    const int p = r / 20, k = r - (r / 20) * 20;
    const int n = b * NN + pbase + p;
    const int j = b * NN + idx[(size_t)n * KK + k];
    const float4 uv = *(const float4*)&U1[(size_t)n * 64 + q * 4];
    const float4 vv = *(const float4*)&V1[(size_t)j * 64 + q * 4];
    float e[4];
    e[0] = fmaxf(uv.x + vv.x, 0.f);
    e[1] = fmaxf(uv.y + vv.y, 0.f);
    e[2] = fmaxf(uv.z + vv.z, 0.f);
    e[3] = fmaxf(uv.w + vv.w, 0.f);
    ushort4 hi, lo;
    hi.x = f2bf(e[0]); lo.x = f2bf(e[0] - bf2f(hi.x));
    hi.y = f2bf(e[1]); lo.y = f2bf(e[1] - bf2f(hi.y));
    hi.z = f2bf(e[2]); lo.z = f2bf(e[2] - bf2f(hi.z));
    hi.w = f2bf(e[3]); lo.w = f2bf(e[3] - bf2f(hi.w));
    *(ushort4*)&A[r][0][q * 4] = hi;
    *(ushort4*)&A[r][1][q * 4] = lo;
  }
  for (int i = t; i < 512; i += 256) ((unsigned int*)pm)[i] = 0u;
  __syncthreads();

  {
    bf16x8 whi[2], wlo[2];
#pragma unroll
    for (int ks = 0; ks < 2; ++ks) {
      whi[ks] = *(const bf16x8*)&w2hi[(size_t)c * 64 + ks * 32 + lk8];
      wlo[ks] = *(const bf16x8*)&w2lo[(size_t)c * 64 + ks * 32 + lk8];
    }
    f32x4 acc2[10];
#pragma unroll
    for (int mt = 0; mt < 10; ++mt) {
      bf16x8 ahi[2], alo[2];
#pragma unroll
      for (int ks = 0; ks < 2; ++ks) {
        ahi[ks] = *(const bf16x8*)&A[mt * 16 + lrow][0][ks * 32 + lk8];
        alo[ks] = *(const bf16x8*)&A[mt * 16 + lrow][1][ks * 32 + lk8];
      }
      f32x4 acc = {0.f, 0.f, 0.f, 0.f};
#pragma unroll
      for (int ks = 0; ks < 2; ++ks) {
        acc = __builtin_amdgcn_mfma_f32_16x16x32_bf16(ahi[ks], whi[ks], acc, 0, 0, 0);
        acc = __builtin_amdgcn_mfma_f32_16x16x32_bf16(ahi[ks], wlo[ks], acc, 0, 0, 0);
        acc = __builtin_amdgcn_mfma_f32_16x16x32_bf16(alo[ks], whi[ks], acc, 0, 0, 0);
      }
      acc2[mt] = acc;
    }
    __syncthreads();
    const float bias = b2[c];
#pragma unroll
    for (int mt = 0; mt < 10; ++mt) {
      const int r0 = mt * 16 + ((lane >> 4) << 2);
#pragma unroll
      for (int reg = 0; reg < 4; ++reg) {
        const float v = fmaxf(acc2[mt][reg] + bias, 0.f);
        const unsigned short h = f2bf(v);
        A[r0 + reg][0][c] = h;
        A[r0 + reg][1][c] = f2bf(v - bf2f(h));
      }
    }
  }
  __syncthreads();

  {
    bf16x8 whi[2], wlo[2];
#pragma unroll
    for (int ks = 0; ks < 2; ++ks) {
      whi[ks] = *(const bf16x8*)&w3hi[(size_t)c * 64 + ks * 32 + lk8];
      wlo[ks] = *(const bf16x8*)&w3lo[(size_t)c * 64 + ks * 32 + lk8];
    }
    const float bias = b3[c];
#pragma unroll
    for (int mt = 0; mt < 10; ++mt) {
      bf16x8 ahi[2], alo[2];
#pragma unroll
      for (int ks = 0; ks < 2; ++ks) {
        ahi[ks] = *(const bf16x8*)&A[mt * 16 + lrow][0][ks * 32 + lk8];
        alo[ks] = *(const bf16x8*)&A[mt * 16 + lrow][1][ks * 32 + lk8];
      }
      f32x4 acc = {0.f, 0.f, 0.f, 0.f};
#pragma unroll
      for (int ks = 0; ks < 2; ++ks) {
        acc = __builtin_amdgcn_mfma_f32_16x16x32_bf16(ahi[ks], whi[ks], acc, 0, 0, 0);
        acc = __builtin_amdgcn_mfma_f32_16x16x32_bf16(ahi[ks], wlo[ks], acc, 0, 0, 0);
        acc = __builtin_amdgcn_mfma_f32_16x16x32_bf16(alo[ks], whi[ks], acc, 0, 0, 0);
      }
      const int r0 = mt * 16 + ((lane >> 4) << 2);
      const float v0 = fmaxf(acc[0] + bias, 0.f);
      const float v1 = fmaxf(acc[1] + bias, 0.f);
      const float v2 = fmaxf(acc[2] + bias, 0.f);
      const float v3 = fmaxf(acc[3] + bias, 0.f);
      if (r0 / 20 == (r0 + 3) / 20) {
        atomicMax(&pm[r0 / 20][c], __float_as_uint(fmaxf(fmaxf(v0, v1), fmaxf(v2, v3))));
      } else {
        atomicMax(&pm[(r0 + 0) / 20][c], __float_as_uint(v0));
        atomicMax(&pm[(r0 + 1) / 20][c], __float_as_uint(v1));
        atomicMax(&pm[(r0 + 2) / 20][c], __float_as_uint(v2));
        atomicMax(&pm[(r0 + 3) / 20][c], __float_as_uint(v3));
      }
    }
  }
  __syncthreads();

  {
    const int p = t >> 5;
    const int cc = (t & 31) * 2;
    float2 o;
    o.x = __uint_as_float(pm[p][cc]);
    o.y = __uint_as_float(pm[p][cc + 1]);
    *(float2*)&xout[((size_t)(b * NN + pbase + p)) * 64 + cc] = o;
  }
}

// ---------------------------------------------------------------------------
// xsplit: x1 (fp32) -> xhi/xlo (split bf16) + s = sum(x^2) fp32.
// ---------------------------------------------------------------------------
__global__ __launch_bounds__(256) void xsplit_kernel(const float* __restrict__ x1,
                                                     unsigned short* __restrict__ xhi,
                                                     unsigned short* __restrict__ xlo,
                                                     float* __restrict__ s) {
  const int e = blockIdx.x * 256 + threadIdx.x;  // 131072 total
  const int n = e >> 3, q = e & 7;
  const float4 v0 = *(const float4*)&x1[(size_t)n * 64 + q * 8];
  const float4 v1 = *(const float4*)&x1[(size_t)n * 64 + q * 8 + 4];
  float ps = v0.x * v0.x + v0.y * v0.y + v0.z * v0.z + v0.w * v0.w +
             v1.x * v1.x + v1.y * v1.y + v1.z * v1.z + v1.w * v1.w;
  ps += __shfl_xor(ps, 1);
  ps += __shfl_xor(ps, 2);
  ps += __shfl_xor(ps, 4);
  if (q == 0) s[n] = ps;
  const float vv[8] = {v0.x, v0.y, v0.z, v0.w, v1.x, v1.y, v1.z, v1.w};
  unsigned short hb[8], lb[8];
#pragma unroll
  for (int i = 0; i < 8; ++i) {
    hb[i] = f2bf(vv[i]);
    lb[i] = f2bf(vv[i] - bf2f(hb[i]));
  }
  *(ushort4*)&xhi[(size_t)n * 64 + q * 8] = make_ushort4(hb[0], hb[1], hb[2], hb[3]);
  *(ushort4*)&xhi[(size_t)n * 64 + q * 8 + 4] = make_ushort4(hb[4], hb[5], hb[6], hb[7]);
  *(ushort4*)&xlo[(size_t)n * 64 + q * 8] = make_ushort4(lb[0], lb[1], lb[2], lb[3]);
  *(ushort4*)&xlo[(size_t)n * 64 + q * 8 + 4] = make_ushort4(lb[4], lb[5], lb[6], lb[7]);
}

// ---------------------------------------------------------------------------
// d2 + fused partial selection, split-bf16 MFMA GEMM. 512-thread blocks:
// 8 waves x (16 rows x 128 cols) GEMM; selection = 4 threads/column x 32
// rows, snapshot shfl merges (stride 1,2), lane-indexed shfl prefix for the
// two-category emission. Same LDS; 2 blocks/CU -> 16 waves/CU (was 8).
// ---------------------------------------------------------------------------
__global__ __launch_bounds__(512) void d2sel_kernel(const unsigned short* __restrict__ xhi,
                                                    const unsigned short* __restrict__ xlo,
                                                    const float* __restrict__ s,
                                                    float* __restrict__ candd,
                                                    int* __restrict__ candi) {
  __shared__ __align__(16) unsigned short SBUF[4 * 128 * 72];
  __shared__ float sA[128], sB[128];
  float (*Tt)[132] = (float(*)[132])SBUF;
  const int bid = blockIdx.x;
  const int b = bid >> 8;
  const int tile = bid & 255;
  const int ti = tile >> 4, tj = tile & 15;
  const int i0 = ti * 128, j0 = tj * 128;
  const int gb = b * NN;
  const int t = threadIdx.x;
  const int wave = t >> 6, lane = t & 63;
  const int lrow = lane & 15;
  const int lk8 = (lane >> 4) * 8;

  for (int it = t; it < 4096; it += 512) {
    const int part = it >> 10;           // 0:AH 1:AL 2:BH 3:BL
    const int r = (it >> 3) & 127;
    const int g = it & 7;
    const unsigned short* src = (part == 0) ? xhi : (part == 1) ? xlo
                               : (part == 2) ? xhi : xlo;
    const int base = (part < 2) ? i0 : j0;
    *(uint4*)&SBUF[part * 9216 + r * 72 + g * 8] =
        *(const uint4*)&src[((size_t)(gb + base + r)) * 64 + g * 8];
  }
  if (t < 128) sA[t] = s[gb + i0 + t];
  else if (t < 256) sB[t - 128] = s[gb + j0 + (t - 128)];
  __syncthreads();

  // ---- GEMM: wave owns rows wave*16..+15; acc[nt] over 8 N-tiles
  bf16x8 ahi[2], alo[2];
  {
    const int r = wave * 16 + lrow;
#pragma unroll
    for (int ks = 0; ks < 2; ++ks) {
      ahi[ks] = *(const bf16x8*)&SBUF[0 * 9216 + r * 72 + ks * 32 + lk8];
      alo[ks] = *(const bf16x8*)&SBUF[1 * 9216 + r * 72 + ks * 32 + lk8];
    }
  }
  f32x4 acc[8];
#pragma unroll
  for (int nt = 0; nt < 8; ++nt) acc[nt] = (f32x4){0.f, 0.f, 0.f, 0.f};
#pragma unroll
  for (int nt = 0; nt < 8; ++nt) {
    bf16x8 bhi[2], blo[2];
#pragma unroll
    for (int ks = 0; ks < 2; ++ks) {
      bhi[ks] = *(const bf16x8*)&SBUF[2 * 9216 + (nt * 16 + lrow) * 72 + ks * 32 + lk8];
      blo[ks] = *(const bf16x8*)&SBUF[3 * 9216 + (nt * 16 + lrow) * 72 + ks * 32 + lk8];
    }
#pragma unroll
    for (int ks = 0; ks < 2; ++ks) {
      acc[nt] = __builtin_amdgcn_mfma_f32_16x16x32_bf16(ahi[ks], bhi[ks], acc[nt], 0, 0, 0);
      acc[nt] = __builtin_amdgcn_mfma_f32_16x16x32_bf16(ahi[ks], blo[ks], acc[nt], 0, 0, 0);
      acc[nt] = __builtin_amdgcn_mfma_f32_16x16x32_bf16(alo[ks], bhi[ks], acc[nt], 0, 0, 0);
    }
  }
  __syncthreads();   // all stage reads done before Tt overlays SBUF

  // ---- Tt[j][i] = sA[i] + sB[j] - 2*dot (float4 stores along i)
  {
    const int ib = wave * 16 + ((lane >> 4) << 2);
#pragma unroll
    for (int nt = 0; nt < 8; ++nt) {
      const int jj = nt * 16 + lrow;
      const float sj = sB[jj];
      float4 o;
      o.x = sA[ib + 0] + sj - 2.f * acc[nt][0];
      o.y = sA[ib + 1] + sj - 2.f * acc[nt][1];
      o.z = sA[ib + 2] + sj - 2.f * acc[nt][2];
      o.w = sA[ib + 3] + sj - 2.f * acc[nt][3];
      *(float4*)&Tt[jj][ib] = o;
    }
  }
  __syncthreads();

  // ---- pass 1: 4 threads/column, each scans 32 rows; snapshot merges
  const int j = t >> 2, h = t & 3;
  float sl[KK];
#pragma unroll
  for (int q = 0; q < KK; ++q) sl[q] = INFINITY;
  for (int r4 = 0; r4 < 8; ++r4) {
    const float4 v = *(const float4*)&Tt[j][h * 32 + r4 * 4];
    sins20(sl, v.x);
    sins20(sl, v.y);
    sins20(sl, v.z);
    sins20(sl, v.w);
  }
  {
    float od[KK];
#pragma unroll
    for (int q = 0; q < KK; ++q) od[q] = __shfl_xor(sl[q], 1);
#pragma unroll
    for (int q = 0; q < KK; ++q) sins20(sl, od[q]);
#pragma unroll
    for (int q = 0; q < KK; ++q) od[q] = __shfl_xor(sl[q], 2);
#pragma unroll
    for (int q = 0; q < KK; ++q) sins20(sl, od[q]);
  }
  const float tau = sl[0];

  // ---- pass 2: counts over own 32 rows; lane-indexed gather for prefixes
  int cA = 0, cB = 0;
  for (int r4 = 0; r4 < 8; ++r4) {
    const float4 v = *(const float4*)&Tt[j][h * 32 + r4 * 4];
    cA += (v.x < tau) + (v.y < tau) + (v.z < tau) + (v.w < tau);
    cB += (v.x == tau) + (v.y == tau) + (v.z == tau) + (v.w == tau);
  }
  const int lb = lane & ~3;
  int aArr[4], bArr[4];
#pragma unroll
  for (int g = 0; g < 4; ++g) {
    aArr[g] = __shfl(cA, lb + g);
    bArr[g] = __shfl(cB, lb + g);
  }
  const int nAtot = aArr[0] + aArr[1] + aArr[2] + aArr[3];   // <= 19
  int prefA = 0, prefB = 0;
  if (h > 0) { prefA += aArr[0]; prefB += bArr[0]; }
  if (h > 1) { prefA += aArr[1]; prefB += bArr[1]; }
  if (h > 2) { prefA += aArr[2]; prefB += bArr[2]; }
  int posA = prefA;
  int posB = nAtot + prefB;

  // ---- pass 3: emission (A: all d<tau in row order; B: d==tau capped at 20)
  const size_t obase = ((size_t)(b * 16 + ti) * KK) * 2048 + (j0 + j);
  for (int r4 = 0; r4 < 8; ++r4) {
    const float4 v = *(const float4*)&Tt[j][h * 32 + r4 * 4];
    const float dd[4] = {v.x, v.y, v.z, v.w};
#pragma unroll
    for (int u = 0; u < 4; ++u) {
      const float d = dd[u];
      const int row = i0 + h * 32 + r4 * 4 + u;
      if (d < tau) {
        candd[obase + (size_t)posA * 2048] = d;
        candi[obase + (size_t)posA * 2048] = row;
        ++posA;
      } else if (d == tau && posB < KK) {
        candd[obase + (size_t)posB * 2048] = d;
        candi[obase + (size_t)posB * 2048] = row;
        ++posB;
      }
    }
  }
}

// ---------------------------------------------------------------------------
// conv2 EdgeConv layers 2,3 via bf16 MFMA; in-place E; split-bf16 x2 out.
// ---------------------------------------------------------------------------
__global__ __launch_bounds__(256) void conv2_kernel(
    const float* __restrict__ U, const float* __restrict__ V,
    const int* __restrict__ idx,
    const unsigned short* __restrict__ w2t, const float* __restrict__ b2,
    const unsigned short* __restrict__ w3t, const float* __restrict__ b3,
    unsigned short* __restrict__ x2hi, unsigned short* __restrict__ x2lo) {
  __shared__ __align__(16) unsigned short E[80][136];
  __shared__ unsigned int pm[4][256];
  const int bid = blockIdx.x;
  const int b = bid >> 9;
  const int pbase = (bid & 511) * 4;
  const int t = threadIdx.x;
  const int wave = t >> 6, lane = t & 63;
  const int lrow = lane & 15;
  const int lk8 = (lane >> 4) * 8;

  for (int it = t; it < 2560; it += 256) {
    const int r = it >> 5, q = it & 31;
    const int p = r / 20, k = r - (r / 20) * 20;
    const int n = b * NN + pbase + p;
    const int j = b * NN + idx[(size_t)n * KK + k];
    const float4 uv = *(const float4*)&U[(size_t)n * 128 + q * 4];
    const float4 vv = *(const float4*)&V[(size_t)j * 128 + q * 4];
    ushort4 h;
    h.x = f2bf(fmaxf(uv.x + vv.x, 0.f));
    h.y = f2bf(fmaxf(uv.y + vv.y, 0.f));
    h.z = f2bf(fmaxf(uv.z + vv.z, 0.f));
    h.w = f2bf(fmaxf(uv.w + vv.w, 0.f));
    *(ushort4*)&E[r][q * 4] = h;
  }
  for (int i = t; i < 1024; i += 256) ((unsigned int*)pm)[i] = 0u;
  __syncthreads();

  // ---- layer 2: [80x128] @ [128x128], in-place (accs reg-buffered)
  {
    bf16x8 wf[2][4];
#pragma unroll
    for (int nt2 = 0; nt2 < 2; ++nt2) {
      const int ntg = wave * 2 + nt2;
#pragma unroll
      for (int ks = 0; ks < 4; ++ks)
        wf[nt2][ks] = *(const bf16x8*)&w2t[(size_t)(ntg * 16 + lrow) * 128 + ks * 32 + lk8];
    }
    f32x4 a0buf[5], a1buf[5];
#pragma unroll
    for (int mt = 0; mt < 5; ++mt) {
      bf16x8 af[4];
#pragma unroll
      for (int ks = 0; ks < 4; ++ks)
        af[ks] = *(const bf16x8*)&E[mt * 16 + lrow][ks * 32 + lk8];
      f32x4 acc0 = {0.f, 0.f, 0.f, 0.f};
      f32x4 acc1 = {0.f, 0.f, 0.f, 0.f};
#pragma unroll
      for (int ks = 0; ks < 4; ++ks) {
        acc0 = __builtin_amdgcn_mfma_f32_16x16x32_bf16(af[ks], wf[0][ks], acc0, 0, 0, 0);
        acc1 = __builtin_amdgcn_mfma_f32_16x16x32_bf16(af[ks], wf[1][ks], acc1, 0, 0, 0);
      }
      a0buf[mt] = acc0;
      a1buf[mt] = acc1;
    }
    __syncthreads();   // all layer-2 E reads done before overwrite
    const float bias0 = b2[wave * 32 + lrow];
    const float bias1 = b2[wave * 32 + 16 + lrow];
#pragma unroll
    for (int mt = 0; mt < 5; ++mt) {
      const int r0 = mt * 16 + ((lane >> 4) << 2);
      const int c0 = wave * 32 + lrow;
#pragma unroll
      for (int reg = 0; reg < 4; ++reg) {
        E[r0 + reg][c0]      = f2bf(fmaxf(a0buf[mt][reg] + bias0, 0.f));
        E[r0 + reg][c0 + 16] = f2bf(fmaxf(a1buf[mt][reg] + bias1, 0.f));
      }
    }
  }
  __syncthreads();

  // ---- layer 3: [80x128] @ [128x256], relu+bias, max over edges into pm
  {
    bf16x8 wf[4][4];
#pragma unroll
    for (int nt4 = 0; nt4 < 4; ++nt4) {
      const int ntg = wave * 4 + nt4;
#pragma unroll
      for (int ks = 0; ks < 4; ++ks)
        wf[nt4][ks] = *(const bf16x8*)&w3t[(size_t)(ntg * 16 + lrow) * 128 + ks * 32 + lk8];
    }
#pragma unroll
    for (int mt = 0; mt < 5; ++mt) {
      bf16x8 af[4];
#pragma unroll
      for (int ks = 0; ks < 4; ++ks)
        af[ks] = *(const bf16x8*)&E[mt * 16 + lrow][ks * 32 + lk8];
      f32x4 acc[4];
#pragma unroll
      for (int nt4 = 0; nt4 < 4; ++nt4) acc[nt4] = (f32x4){0.f, 0.f, 0.f, 0.f};
#pragma unroll
      for (int ks = 0; ks < 4; ++ks) {
#pragma unroll
        for (int nt4 = 0; nt4 < 4; ++nt4)
          acc[nt4] = __builtin_amdgcn_mfma_f32_16x16x32_bf16(af[ks], wf[nt4][ks], acc[nt4], 0, 0, 0);
      }
      const int r0 = mt * 16 + ((lane >> 4) << 2);
      const int pa = r0 / 20;
      const int pb = (r0 + 3) / 20;
#pragma unroll
      for (int nt4 = 0; nt4 < 4; ++nt4) {
        const int c = wave * 64 + nt4 * 16 + lrow;
        const float bias = b3[c];
        float v0 = fmaxf(acc[nt4][0] + bias, 0.f);
        float v1 = fmaxf(acc[nt4][1] + bias, 0.f);
        float v2 = fmaxf(acc[nt4][2] + bias, 0.f);
        float v3 = fmaxf(acc[nt4][3] + bias, 0.f);
        if (pa == pb) {
          atomicMax(&pm[pa][c], __float_as_uint(fmaxf(fmaxf(v0, v1), fmaxf(v2, v3))));
        } else {
          atomicMax(&pm[(r0 + 0) / 20][c], __float_as_uint(v0));
          atomicMax(&pm[(r0 + 1) / 20][c], __float_as_uint(v1));
          atomicMax(&pm[(r0 + 2) / 20][c], __float_as_uint(v2));
          atomicMax(&pm[(r0 + 3) / 20][c], __float_as_uint(v3));
        }
      }
    }
  }
  __syncthreads();

  // ---- write split-bf16 x2 (values >= 0)
  {
    const int p = t >> 6;
    const int c0 = (t & 63) * 4;
    const float4 o = *(const float4*)&pm[p][c0];
    ushort4 hi, lo;
    hi.x = f2bf(o.x); lo.x = f2bf(o.x - bf2f(hi.x));
    hi.y = f2bf(o.y); lo.y = f2bf(o.y - bf2f(hi.y));
    hi.z = f2bf(o.z); lo.z = f2bf(o.z - bf2f(hi.z));
    hi.w = f2bf(o.w); lo.w = f2bf(o.w - bf2f(hi.w));
    const size_t base = ((size_t)b * NN + pbase + p) * 256 + c0;
    *(ushort4*)&x2hi[base] = hi;
    *(ushort4*)&x2lo[base] = lo;
  }
}

// ---------------------------------------------------------------------------
// l0 via split-bf16 MFMA (unchanged, proven R10).
// ---------------------------------------------------------------------------
__global__ __launch_bounds__(256) void l0_kernel(
    const unsigned short* __restrict__ x2hi, const unsigned short* __restrict__ x2lo,
    const unsigned short* __restrict__ l0thi, const unsigned short* __restrict__ l0tlo,
    const float* __restrict__ bias, float* __restrict__ gp) {
  __shared__ __align__(16) unsigned short Ahi[64][72];
  __shared__ __align__(16) unsigned short Alo[64][72];
  __shared__ unsigned int pm[256];
  const int bid = blockIdx.x;
  const int cblk = bid & 1;
  const int mblk = (bid >> 1) & 31;
  const int b = bid >> 6;
  const int t = threadIdx.x;
  const int wave = t >> 6, lane = t & 63;
  const int lrow = lane & 15;
  const int lk8 = (lane >> 4) * 8;
  const size_t rowbase = (size_t)(b * NN + mblk * 64);
  const int cbase = cblk * 256;

  pm[t] = 0u;

  f32x4 acc[4][4];
#pragma unroll
  for (int mt = 0; mt < 4; ++mt)
#pragma unroll
    for (int nt = 0; nt < 4; ++nt) acc[mt][nt] = (f32x4){0.f, 0.f, 0.f, 0.f};

  for (int kc = 0; kc < 4; ++kc) {
    for (int it = t; it < 1024; it += 256) {
      const int buf = it >> 9;
      const int r = (it >> 3) & 63;
      const int g = it & 7;
      const unsigned short* src = buf ? x2lo : x2hi;
      const uint4 v = *(const uint4*)&src[(rowbase + r) * 256 + kc * 64 + g * 8];
      if (buf) *(uint4*)&Alo[r][g * 8] = v;
      else     *(uint4*)&Ahi[r][g * 8] = v;
    }
    __syncthreads();

    bf16x8 bhi[4][2], blo[4][2];
#pragma unroll
    for (int nt = 0; nt < 4; ++nt) {
      const size_t c = (size_t)(cbase + wave * 64 + nt * 16 + lrow);
#pragma unroll
      for (int ks = 0; ks < 2; ++ks) {
        bhi[nt][ks] = *(const bf16x8*)&l0thi[c * 256 + kc * 64 + ks * 32 + lk8];
        blo[nt][ks] = *(const bf16x8*)&l0tlo[c * 256 + kc * 64 + ks * 32 + lk8];
      }
    }
#pragma unroll
    for (int mt = 0; mt < 4; ++mt) {
      bf16x8 ahi[2], alo[2];
#pragma unroll
      for (int ks = 0; ks < 2; ++ks) {
        ahi[ks] = *(const bf16x8*)&Ahi[mt * 16 + lrow][ks * 32 + lk8];
        alo[ks] = *(const bf16x8*)&Alo[mt * 16 + lrow][ks * 32 + lk8];
      }
#pragma unroll
      for (int nt = 0; nt < 4; ++nt) {
#pragma unroll
        for (int ks = 0; ks < 2; ++ks) {
          acc[mt][nt] = __builtin_amdgcn_mfma_f32_16x16x32_bf16(ahi[ks], bhi[nt][ks], acc[mt][nt], 0, 0, 0);
          acc[mt][nt] = __builtin_amdgcn_mfma_f32_16x16x32_bf16(ahi[ks], blo[nt][ks], acc[mt][nt], 0, 0, 0);
          acc[mt][nt] = __builtin_amdgcn_mfma_f32_16x16x32_bf16(alo[ks], bhi[nt][ks], acc[mt][nt], 0, 0, 0);
        }
      }
    }
    __syncthreads();
  }

#pragma unroll
  for (int nt = 0; nt < 4; ++nt) {
    const int cl = wave * 64 + nt * 16 + lrow;
    const float bv = bias[cbase + cl];
    float mx = 0.f;
#pragma unroll
    for (int mt = 0; mt < 4; ++mt)
#pragma unroll
      for (int reg = 0; reg < 4; ++reg)
        mx = fmaxf(mx, fmaxf(acc[mt][nt][reg] + bv, 0.f));
    atomicMax(&pm[cl], __float_as_uint(mx));
  }
  __syncthreads();
  gp[((size_t)(b * 32 + mblk)) * 512 + cbase + t] = __uint_as_float(pm[t]);
}

// ---------------------------------------------------------------------------
// final pool-reduce (32 partials) + classifier head + log_softmax (unchanged).
// ---------------------------------------------------------------------------
__global__ __launch_bounds__(256) void head_kernel(
    const float* __restrict__ gp,
    const float* __restrict__ l1w, const float* __restrict__ l1b,
    const float* __restrict__ l2w, const float* __restrict__ l2b,
    const float* __restrict__ l3w, const float* __restrict__ l3b,
    float* __restrict__ out) {
  __shared__ float g[512];
  __shared__ float h1[256];
  __shared__ float h2[256];
  __shared__ float logits[40];
  __shared__ float lse_s;
  const int b = blockIdx.x;
  const int t = threadIdx.x;
  for (int cidx = t; cidx < 512; cidx += 256) {
    float m = gp[(size_t)(b * 32) * 512 + cidx];
    for (int ch = 1; ch < 32; ++ch) m = fmaxf(m, gp[(size_t)(b * 32 + ch) * 512 + cidx]);
    g[cidx] = m;
  }
  __syncthreads();
  {
    float acc = 0.f;
    for (int d = 0; d < 512; d += 4) {
      const float4 gv = *(const float4*)&g[d];
      acc = fmaf(gv.x, l1w[(size_t)d * 256 + t], acc);
      acc = fmaf(gv.y, l1w[(size_t)(d + 1) * 256 + t], acc);
      acc = fmaf(gv.z, l1w[(size_t)(d + 2) * 256 + t], acc);
      acc = fmaf(gv.w, l1w[(size_t)(d + 3) * 256 + t], acc);
    }
    h1[t] = fmaxf(acc + l1b[t], 0.f);
  }
  __syncthreads();
  {
    float acc = 0.f;
    for (int d = 0; d < 256; d += 4) {
      const float4 hv = *(const float4*)&h1[d];
      acc = fmaf(hv.x, l2w[(size_t)d * 256 + t], acc);
      acc = fmaf(hv.y, l2w[(size_t)(d + 1) * 256 + t], acc);
      acc = fmaf(hv.z, l2w[(size_t)(d + 2) * 256 + t], acc);
      acc = fmaf(hv.w, l2w[(size_t)(d + 3) * 256 + t], acc);
    }
    h2[t] = fmaxf(acc + l2b[t], 0.f);
  }
  __syncthreads();
  if (t < 40) {
    float acc = 0.f;
    for (int d = 0; d < 256; ++d) acc = fmaf(h2[d], l3w[(size_t)d * 40 + t], acc);
    logits[t] = acc + l3b[t];
  }
  __syncthreads();
  if (t == 0) {
    float M = -INFINITY;
    for (int j = 0; j < 40; ++j) M = fmaxf(M, logits[j]);
    float ssum = 0.f;
    for (int j = 0; j < 40; ++j) ssum += expf(logits[j] - M);
    lse_s = M + logf(ssum);
  }
  __syncthreads();
  if (t < 40) out[(size_t)b * 40 + t] = logits[t] - lse_s;
}

// ---------------------------------------------------------------------------
extern "C" void kernel_launch(void* const* d_in, const int* in_sizes, int n_in,
                              void* d_out, int out_size, void* d_ws, size_t ws_size,
                              hipStream_t stream) {
  const float* pos  = (const float*)d_in[0];
  const float* c1w1 = (const float*)d_in[2];
  const float* c1b1 = (const float*)d_in[3];
  const float* c1w2 = (const float*)d_in[4];
  const float* c1b2 = (const float*)d_in[5];
  const float* c1w3 = (const float*)d_in[6];
  const float* c1b3 = (const float*)d_in[7];
  const float* c2w1 = (const float*)d_in[8];
  const float* c2b1 = (const float*)d_in[9];
  const float* c2w2 = (const float*)d_in[10];
  const float* c2b2 = (const float*)d_in[11];
  const float* c2w3 = (const float*)d_in[12];
  const float* c2b3 = (const float*)d_in[13];
  const float* l0w  = (const float*)d_in[14];
  const float* l0b  = (const float*)d_in[15];
  const float* l1w  = (const float*)d_in[16];
  const float* l1b  = (const float*)d_in[17];
  const float* l2w  = (const float*)d_in[18];
  const float* l2b  = (const float*)d_in[19];
  const float* l3w  = (const float*)d_in[20];
  const float* l3b  = (const float*)d_in[21];
  float* out = (float*)d_out;

  char* ws = (char*)d_ws;
  float* x1    = (float*)(ws + 0);                      // 4 MB    [8,2048,64]
  int*   idx1  = (int*)  (ws + ((size_t)20 << 20));     // 1.31 MB [16384,20]
  int*   idx2  = (int*)  (ws + ((size_t)22 << 20));     // 1.31 MB
  float* gp    = (float*)(ws + ((size_t)24 << 20));     // 512 KB  [8,32,512]
  unsigned short* w2t    = (unsigned short*)(ws + ((size_t)24 << 20) + (512 << 10)); // 32 KB
  unsigned short* w3t    = (unsigned short*)(ws + ((size_t)24 << 20) + (544 << 10)); // 64 KB
  unsigned short* c1w2hi = (unsigned short*)(ws + ((size_t)24 << 20) + (608 << 10)); // 8 KB
  unsigned short* c1w2lo = (unsigned short*)(ws + ((size_t)24 << 20) + (616 << 10)); // 8 KB
  unsigned short* c1w3hi = (unsigned short*)(ws + ((size_t)24 << 20) + (624 << 10)); // 8 KB
  unsigned short* c1w3lo = (unsigned short*)(ws + ((size_t)24 << 20) + (632 << 10)); // 8 KB
  float* candd = (float*)(ws + ((size_t)25 << 20));     // 21 MB   [8,16,20,2048]
  int*   candi = (int*)  (ws + ((size_t)46 << 20));     // 21 MB (ends 67 MB)
  // Overlays (regions dead at time of use):
  float* U1 = (float*)(ws + ((size_t)25 << 20));        // 4 MB over candd (dead after merge1)
  float* V1 = (float*)(ws + ((size_t)29 << 20));        // 4 MB
  float* U  = (float*)(ws + ((size_t)46 << 20));        // 8 MB over candi (dead after merge2)
  float* Vv = (float*)(ws + ((size_t)54 << 20));        // 8 MB (ends at 62 MB)
  // Non-overlapping tail:
  unsigned short* xhi  = (unsigned short*)(ws + ((size_t)68 << 20));  // 2 MB
  unsigned short* xlo  = (unsigned short*)(ws + ((size_t)70 << 20));  // 2 MB
  float*          sbuf = (float*)         (ws + ((size_t)72 << 20));  // 64 KB
  unsigned short* x2hi = (unsigned short*)(ws + ((size_t)73 << 20));  // 8 MB
  unsigned short* x2lo = (unsigned short*)(ws + ((size_t)81 << 20));  // 8 MB
  unsigned short* l0thi = (unsigned short*)(ws + ((size_t)89 << 20));            // 256 KB
  unsigned short* l0tlo = (unsigned short*)(ws + ((size_t)89 << 20) + (256 << 10)); // 256 KB

  wprep_kernel<<<736, 256, 0, stream>>>(c2w2, c2w3, c1w2, c1w3, l0w,
                                        w2t, w3t, c1w2hi, c1w2lo, c1w3hi, c1w3lo,
                                        l0thi, l0tlo);
  knn1_part<<<512, 256, 0, stream>>>(pos, candd, candi);
  merge_topk2<8, 4><<<256, 256, 0, stream>>>(candd, candi, idx1);
  pre1_kernel<<<4096, 256, 0, stream>>>(pos, c1w1, c1b1, U1, V1);      // overwrites candd region
  conv1_kernel<<<2048, 256, 0, stream>>>(U1, V1, idx1, c1w2hi, c1w2lo, c1b2,
                                         c1w3hi, c1w3lo, c1b3, x1);
  xsplit_kernel<<<512, 256, 0, stream>>>(x1, xhi, xlo, sbuf);
  d2sel_kernel<<<2048, 512, 0, stream>>>(xhi, xlo, sbuf, candd, candi); // U1/V1 dead now
  merge_topk2<16, 8><<<512, 256, 0, stream>>>(candd, candi, idx2);
  pre2_kernel<<<256, 256, 0, stream>>>(x1, c2w1, c2b1, U, Vv);         // overwrites candi region
  conv2_kernel<<<4096, 256, 0, stream>>>(U, Vv, idx2, w2t, c2b2, w3t, c2b3, x2hi, x2lo);
  l0_kernel<<<512, 256, 0, stream>>>(x2hi, x2lo, l0thi, l0tlo, l0b, gp);
  head_kernel<<<8, 256, 0, stream>>>(gp, l1w, l1b, l2w, l2b, l3w, l3b, out);
}

// Round 12
// 489.564 us; speedup vs baseline: 1.0445x; 1.0445x over previous
//
#include <hip/hip_runtime.h>
#include <hip/hip_bf16.h>
#include <math.h>

#define BB 8
#define NN 2048
#define KK 20

typedef short bf16x8 __attribute__((ext_vector_type(8)));
typedef float f32x4 __attribute__((ext_vector_type(4)));

// fp32 -> bf16 (round-to-nearest-even), finite inputs only
__device__ __forceinline__ unsigned short f2bf(float f) {
  unsigned u = __float_as_uint(f);
  u += 0x7FFFu + ((u >> 16) & 1u);
  return (unsigned short)(u >> 16);
}
__device__ __forceinline__ float bf2f(unsigned short h) {
  return __uint_as_float(((unsigned)h) << 16);
}

// ---------------------------------------------------------------------------
// top-K (K=20) smallest-value tracker (divergent; used by merge only).
// ---------------------------------------------------------------------------
__device__ __forceinline__ void topk_insert(float d, int m, float (&bd)[KK], int (&bi)[KK],
                                            float& worst, int& wslot) {
  if (d < worst) {
#pragma unroll
    for (int j = 0; j < KK; ++j) {
      if (j == wslot) { bd[j] = d; bi[j] = m; }
    }
    float w = -INFINITY;
    int s = 0;
#pragma unroll
    for (int j = 0; j < KK; ++j) {
      if (bd[j] > w) { w = bd[j]; s = j; }
    }
    worst = w;
    wslot = s;
  }
}

// ---------------------------------------------------------------------------
// Branch-free sorted top-20 VALUE list (descending; s[0] = current 20th
// smallest). Insert = min/max chain, self-filtering.
// ---------------------------------------------------------------------------
__device__ __forceinline__ void sins20(float (&s)[KK], float d) {
#pragma unroll
  for (int q = 0; q < KK - 1; ++q) s[q] = fminf(s[q], fmaxf(s[q + 1], d));
  s[KK - 1] = fminf(s[KK - 1], d);
}

// knn1 distance: explicit fmaf composition -> bit-identical across passes.
__device__ __forceinline__ float knn1_dist(float sn, float ssq,
                                           float x0, float x1, float x2,
                                           float y0, float y1, float y2) {
  const float dot = fmaf(x0, y0, fmaf(x1, y1, x2 * y2));
  return fmaf(-2.f, dot, sn + ssq);
}

// ---------------------------------------------------------------------------
// kNN pass 1 for conv1 (D=3), m-chunked; 3-pass tau selection (proven R9).
// ---------------------------------------------------------------------------
__global__ __launch_bounds__(256) void knn1_part(const float* __restrict__ pos,
                                                 float* __restrict__ candd,
                                                 int* __restrict__ candi) {
  __shared__ float xs0[256], xs1[256], xs2[256], ss[256];
  const int bid = blockIdx.x;
  const int b = bid >> 6;
  const int nc = (bid >> 3) & 7;
  const int mc = bid & 7;
  const int t = threadIdx.x;
  const float* posb = pos + (size_t)b * NN * 3;
  {
    const int m = mc * 256 + t;
    const float a0 = posb[m * 3 + 0];
    const float a1 = posb[m * 3 + 1];
    const float a2 = posb[m * 3 + 2];
    xs0[t] = a0; xs1[t] = a1; xs2[t] = a2;
    ss[t] = a0 * a0 + a1 * a1 + a2 * a2;
  }
  __syncthreads();
  const int n = nc * 256 + t;
  const float xn0 = posb[n * 3 + 0];
  const float xn1 = posb[n * 3 + 1];
  const float xn2 = posb[n * 3 + 2];
  const float sn = xn0 * xn0 + xn1 * xn1 + xn2 * xn2;

  float s[KK];
#pragma unroll
  for (int q = 0; q < KK; ++q) s[q] = INFINITY;
  for (int lm = 0; lm < 256; lm += 8) {
    float dv[8];
#pragma unroll
    for (int u = 0; u < 8; ++u)
      dv[u] = knn1_dist(sn, ss[lm + u], xn0, xn1, xn2, xs0[lm + u], xs1[lm + u], xs2[lm + u]);
#pragma unroll
    for (int u = 0; u < 8; ++u) sins20(s, dv[u]);
  }
  const float tau = s[0];

  int cA = 0;
  for (int lm = 0; lm < 256; lm += 8) {
#pragma unroll
    for (int u = 0; u < 8; ++u) {
      const float d = knn1_dist(sn, ss[lm + u], xn0, xn1, xn2, xs0[lm + u], xs1[lm + u], xs2[lm + u]);
      cA += (d < tau) ? 1 : 0;
    }
  }

  int posA = 0, posB = cA;   // cA <= 19 by definition of tau
  const int rbase = mc * 256;
  const size_t obase = ((size_t)(b * 8 + mc) * KK) * 2048 + n;
  for (int lm = 0; lm < 256; lm += 8) {
#pragma unroll
    for (int u = 0; u < 8; ++u) {
      const float d = knn1_dist(sn, ss[lm + u], xn0, xn1, xn2, xs0[lm + u], xs1[lm + u], xs2[lm + u]);
      if (d < tau) {
        candd[obase + (size_t)posA * 2048] = d;
        candi[obase + (size_t)posA * 2048] = rbase + lm + u;
        ++posA;
      } else if (d == tau && posB < KK) {
        candd[obase + (size_t)posB * 2048] = d;
        candi[obase + (size_t)posB * 2048] = rbase + lm + u;
        ++posB;
      }
    }
  }
}

// ---------------------------------------------------------------------------
// merge v2 (unchanged, proven).
// ---------------------------------------------------------------------------
template <int NCH, int G>
__global__ __launch_bounds__(256) void merge_topk2(const float* __restrict__ candd,
                                                   const int* __restrict__ candi,
                                                   int* __restrict__ idx_out) {
  const int gid = blockIdx.x * 256 + threadIdx.x;
  const int pt = gid / G;
  const int sub = gid % G;
  const int b = pt >> 11, n = pt & 2047;
  constexpr int CPT = NCH / G;
  float bd[KK]; int bi[KK];
#pragma unroll
  for (int j = 0; j < KK; ++j) { bd[j] = INFINITY; bi[j] = 0; }
  float worst = INFINITY;
  int wslot = 0;
#pragma unroll
  for (int cc = 0; cc < CPT; ++cc) {
    const int c = sub * CPT + cc;
    const size_t base = ((size_t)(b * NCH + c) * KK) * 2048 + n;
    float dv[KK]; int iv[KK];
#pragma unroll
    for (int j = 0; j < KK; ++j) dv[j] = candd[base + (size_t)j * 2048];
#pragma unroll
    for (int j = 0; j < KK; ++j) iv[j] = candi[base + (size_t)j * 2048];
#pragma unroll
    for (int j = 0; j < KK; ++j) topk_insert(dv[j], iv[j], bd, bi, worst, wslot);
  }
#pragma unroll
  for (int stride = 1; stride < G; stride <<= 1) {
    float od[KK]; int oi[KK];
#pragma unroll
    for (int q = 0; q < KK; ++q) {
      od[q] = __shfl_xor(bd[q], stride);
      oi[q] = __shfl_xor(bi[q], stride);
    }
#pragma unroll
    for (int q = 0; q < KK; ++q) topk_insert(od[q], oi[q], bd, bi, worst, wslot);
  }
  if (sub == 0) {
    int* op = idx_out + (size_t)pt * KK;
#pragma unroll
    for (int j = 0; j < KK; ++j) op[j] = bi[j];
  }
}

// ---------------------------------------------------------------------------
// pre1: per-point factorized conv1 layer-1.
// ---------------------------------------------------------------------------
__global__ __launch_bounds__(256) void pre1_kernel(const float* __restrict__ pos,
                                                   const float* __restrict__ w1,
                                                   const float* __restrict__ b1,
                                                   float* __restrict__ U1,
                                                   float* __restrict__ V1) {
  const int t = threadIdx.x;
  const int c = t & 63;
  const int n = blockIdx.x * 4 + (t >> 6);
  const float p0 = pos[(size_t)n * 3 + 0];
  const float p1 = pos[(size_t)n * 3 + 1];
  const float p2 = pos[(size_t)n * 3 + 2];
  const float wt0 = w1[0 * 64 + c], wt1 = w1[1 * 64 + c], wt2 = w1[2 * 64 + c];
  const float wb0 = w1[3 * 64 + c], wb1 = w1[4 * 64 + c], wb2 = w1[5 * 64 + c];
  float v = p0 * wb0 + p1 * wb1 + p2 * wb2;
  float u = p0 * (wt0 - wb0) + p1 * (wt1 - wb1) + p2 * (wt2 - wb2) + b1[c];
  U1[(size_t)n * 64 + c] = u;
  V1[(size_t)n * 64 + c] = v;
}

// ---------------------------------------------------------------------------
// pre2: per-point factorized conv2 layer-1 (unchanged).
// ---------------------------------------------------------------------------
__global__ __launch_bounds__(256) void pre2_kernel(const float* __restrict__ x1,
                                                   const float* __restrict__ w1,
                                                   const float* __restrict__ b1,
                                                   float* __restrict__ U,
                                                   float* __restrict__ V) {
  __shared__ float X[64][68];
  const int nbase = blockIdx.x * 64;
  const int t = threadIdx.x;
  for (int it = t; it < 1024; it += 256) {
    const int r = it >> 4, q = it & 15;
    *(float4*)&X[r][q * 4] = *(const float4*)&x1[(size_t)(nbase + r) * 64 + q * 4];
  }
  __syncthreads();
  const int ty = t >> 4, tx = t & 15;
  const int c0 = tx * 8;
  float accT[4][8], accB[4][8];
#pragma unroll
  for (int u = 0; u < 4; ++u)
#pragma unroll
    for (int i = 0; i < 8; ++i) { accT[u][i] = 0.f; accB[u][i] = 0.f; }
  for (int d0 = 0; d0 < 64; d0 += 4) {
    float4 a[4];
#pragma unroll
    for (int u = 0; u < 4; ++u) a[u] = *(const float4*)&X[ty * 4 + u][d0];
#pragma unroll
    for (int dd = 0; dd < 4; ++dd) {
      const float4 t0 = *(const float4*)&w1[(size_t)(d0 + dd) * 128 + c0];
      const float4 t1 = *(const float4*)&w1[(size_t)(d0 + dd) * 128 + c0 + 4];
      const float4 bb0 = *(const float4*)&w1[(size_t)(64 + d0 + dd) * 128 + c0];
      const float4 bb1 = *(const float4*)&w1[(size_t)(64 + d0 + dd) * 128 + c0 + 4];
#pragma unroll
      for (int u = 0; u < 4; ++u) {
        const float av = (dd == 0) ? a[u].x : (dd == 1) ? a[u].y : (dd == 2) ? a[u].z : a[u].w;
        accT[u][0] = fmaf(av, t0.x, accT[u][0]);
        accT[u][1] = fmaf(av, t0.y, accT[u][1]);
        accT[u][2] = fmaf(av, t0.z, accT[u][2]);
        accT[u][3] = fmaf(av, t0.w, accT[u][3]);
        accT[u][4] = fmaf(av, t1.x, accT[u][4]);
        accT[u][5] = fmaf(av, t1.y, accT[u][5]);
        accT[u][6] = fmaf(av, t1.z, accT[u][6]);
        accT[u][7] = fmaf(av, t1.w, accT[u][7]);
        accB[u][0] = fmaf(av, bb0.x, accB[u][0]);
        accB[u][1] = fmaf(av, bb0.y, accB[u][1]);
        accB[u][2] = fmaf(av, bb0.z, accB[u][2]);
        accB[u][3] = fmaf(av, bb0.w, accB[u][3]);
        accB[u][4] = fmaf(av, bb1.x, accB[u][4]);
        accB[u][5] = fmaf(av, bb1.y, accB[u][5]);
        accB[u][6] = fmaf(av, bb1.z, accB[u][6]);
        accB[u][7] = fmaf(av, bb1.w, accB[u][7]);
      }
    }
  }
  const float4 bA = *(const float4*)&b1[c0];
  const float4 bB = *(const float4*)&b1[c0 + 4];
#pragma unroll
  for (int u = 0; u < 4; ++u) {
    const size_t row = (size_t)(nbase + ty * 4 + u) * 128 + c0;
    float4 u0, u1, v0, v1;
    v0 = make_float4(accB[u][0], accB[u][1], accB[u][2], accB[u][3]);
    v1 = make_float4(accB[u][4], accB[u][5], accB[u][6], accB[u][7]);
    u0.x = accT[u][0] - accB[u][0] + bA.x;
    u0.y = accT[u][1] - accB[u][1] + bA.y;
    u0.z = accT[u][2] - accB[u][2] + bA.z;
    u0.w = accT[u][3] - accB[u][3] + bA.w;
    u1.x = accT[u][4] - accB[u][4] + bB.x;
    u1.y = accT[u][5] - accB[u][5] + bB.y;
    u1.z = accT[u][6] - accB[u][6] + bB.z;
    u1.w = accT[u][7] - accB[u][7] + bB.w;
    *(float4*)&U[row] = u0;
    *(float4*)&U[row + 4] = u1;
    *(float4*)&V[row] = v0;
    *(float4*)&V[row + 4] = v1;
  }
}

// ---------------------------------------------------------------------------
// wprep: transpose+convert weights for MFMA B-fragments.
// ---------------------------------------------------------------------------
__global__ __launch_bounds__(256) void wprep_kernel(
    const float* __restrict__ c2w2, const float* __restrict__ c2w3,
    const float* __restrict__ c1w2, const float* __restrict__ c1w3,
    const float* __restrict__ l0w,
    unsigned short* __restrict__ w2t, unsigned short* __restrict__ w3t,
    unsigned short* __restrict__ c1w2hi, unsigned short* __restrict__ c1w2lo,
    unsigned short* __restrict__ c1w3hi, unsigned short* __restrict__ c1w3lo,
    unsigned short* __restrict__ l0thi, unsigned short* __restrict__ l0tlo) {
  const int i = blockIdx.x * 256 + threadIdx.x;
  if (i < 16384) {
    const int d = i >> 7, c = i & 127;
    w2t[c * 128 + d] = f2bf(c2w2[i]);
  } else if (i < 49152) {
    const int j = i - 16384;
    const int d = j >> 8, c = j & 255;
    w3t[c * 128 + d] = f2bf(c2w3[j]);
  } else if (i < 53248) {
    const int j = i - 49152;
    const int d = j >> 6, c = j & 63;
    const float v = c1w2[j];
    const unsigned short h = f2bf(v);
    c1w2hi[c * 64 + d] = h;
    c1w2lo[c * 64 + d] = f2bf(v - bf2f(h));
  } else if (i < 57344) {
    const int j = i - 53248;
    const int d = j >> 6, c = j & 63;
    const float v = c1w3[j];
    const unsigned short h = f2bf(v);
    c1w3hi[c * 64 + d] = h;
    c1w3lo[c * 64 + d] = f2bf(v - bf2f(h));
  } else if (i < 188416) {
    const int j = i - 57344;             // < 131072 = 256*512
    const int d = j >> 9, c = j & 511;
    const float v = l0w[j];
    const unsigned short h = f2bf(v);
    l0thi[c * 256 + d] = h;
    l0tlo[c * 256 + d] = f2bf(v - bf2f(h));
  }
}

// ---------------------------------------------------------------------------
// conv1 EdgeConv layers 2,3 via SPLIT-bf16 MFMA; epilogue now FUSES xsplit:
// writes x1 (fp32, for pre2) AND xhi/xlo (split bf16) AND s = sum(x^2)
// (32-lane shfl_xor tree, deterministic).
// ---------------------------------------------------------------------------
__global__ __launch_bounds__(256) void conv1_kernel(
    const float* __restrict__ U1, const float* __restrict__ V1,
    const int* __restrict__ idx,
    const unsigned short* __restrict__ w2hi, const unsigned short* __restrict__ w2lo,
    const float* __restrict__ b2,
    const unsigned short* __restrict__ w3hi, const unsigned short* __restrict__ w3lo,
    const float* __restrict__ b3,
    float* __restrict__ xout,
    unsigned short* __restrict__ xhi, unsigned short* __restrict__ xlo,
    float* __restrict__ sbuf) {
  __shared__ __align__(16) unsigned short A[160][2][76];
  __shared__ unsigned int pm[8][64];
  const int bid = blockIdx.x;
  const int b = bid >> 8;
  const int pbase = (bid & 255) * 8;
  const int t = threadIdx.x;
  const int wave = t >> 6, lane = t & 63;
  const int lrow = lane & 15;
  const int lk8 = (lane >> 4) * 8;
  const int c = wave * 16 + lrow;

  for (int it = t; it < 2560; it += 256) {
    const int r = it >> 4, q = it & 15;
    const int p = r / 20, k = r - (r / 20) * 20;
    const int n = b * NN + pbase + p;
    const int j = b * NN + idx[(size_t)n * KK + k];
    const float4 uv = *(const float4*)&U1[(size_t)n * 64 + q * 4];
    const float4 vv = *(const float4*)&V1[(size_t)j * 64 + q * 4];
    float e[4];
    e[0] = fmaxf(uv.x + vv.x, 0.f);
    e[1] = fmaxf(uv.y + vv.y, 0.f);
    e[2] = fmaxf(uv.z + vv.z, 0.f);
    e[3] = fmaxf(uv.w + vv.w, 0.f);
    ushort4 hi, lo;
    hi.x = f2bf(e[0]); lo.x = f2bf(e[0] - bf2f(hi.x));
    hi.y = f2bf(e[1]); lo.y = f2bf(e[1] - bf2f(hi.y));
    hi.z = f2bf(e[2]); lo.z = f2bf(e[2] - bf2f(hi.z));
    hi.w = f2bf(e[3]); lo.w = f2bf(e[3] - bf2f(hi.w));
    *(ushort4*)&A[r][0][q * 4] = hi;
    *(ushort4*)&A[r][1][q * 4] = lo;
  }
  for (int i = t; i < 512; i += 256) ((unsigned int*)pm)[i] = 0u;
  __syncthreads();

  {
    bf16x8 whi[2], wlo[2];
#pragma unroll
    for (int ks = 0; ks < 2; ++ks) {
      whi[ks] = *(const bf16x8*)&w2hi[(size_t)c * 64 + ks * 32 + lk8];
      wlo[ks] = *(const bf16x8*)&w2lo[(size_t)c * 64 + ks * 32 + lk8];
    }
    f32x4 acc2[10];
#pragma unroll
    for (int mt = 0; mt < 10; ++mt) {
      bf16x8 ahi[2], alo[2];
#pragma unroll
      for (int ks = 0; ks < 2; ++ks) {
        ahi[ks] = *(const bf16x8*)&A[mt * 16 + lrow][0][ks * 32 + lk8];
        alo[ks] = *(const bf16x8*)&A[mt * 16 + lrow][1][ks * 32 + lk8];
      }
      f32x4 acc = {0.f, 0.f, 0.f, 0.f};
#pragma unroll
      for (int ks = 0; ks < 2; ++ks) {
        acc = __builtin_amdgcn_mfma_f32_16x16x32_bf16(ahi[ks], whi[ks], acc, 0, 0, 0);
        acc = __builtin_amdgcn_mfma_f32_16x16x32_bf16(ahi[ks], wlo[ks], acc, 0, 0, 0);
        acc = __builtin_amdgcn_mfma_f32_16x16x32_bf16(alo[ks], whi[ks], acc, 0, 0, 0);
      }
      acc2[mt] = acc;
    }
    __syncthreads();
    const float bias = b2[c];
#pragma unroll
    for (int mt = 0; mt < 10; ++mt) {
      const int r0 = mt * 16 + ((lane >> 4) << 2);
#pragma unroll
      for (int reg = 0; reg < 4; ++reg) {
        const float v = fmaxf(acc2[mt][reg] + bias, 0.f);
        const unsigned short h = f2bf(v);
        A[r0 + reg][0][c] = h;
        A[r0 + reg][1][c] = f2bf(v - bf2f(h));
      }
    }
  }
  __syncthreads();

  {
    bf16x8 whi[2], wlo[2];
#pragma unroll
    for (int ks = 0; ks < 2; ++ks) {
      whi[ks] = *(const bf16x8*)&w3hi[(size_t)c * 64 + ks * 32 + lk8];
      wlo[ks] = *(const bf16x8*)&w3lo[(size_t)c * 64 + ks * 32 + lk8];
    }
    const float bias = b3[c];
#pragma unroll
    for (int mt = 0; mt < 10; ++mt) {
      bf16x8 ahi[2], alo[2];
#pragma unroll
      for (int ks = 0; ks < 2; ++ks) {
        ahi[ks] = *(const bf16x8*)&A[mt * 16 + lrow][0][ks * 32 + lk8];
        alo[ks] = *(const bf16x8*)&A[mt * 16 + lrow][1][ks * 32 + lk8];
      }
      f32x4 acc = {0.f, 0.f, 0.f, 0.f};
#pragma unroll
      for (int ks = 0; ks < 2; ++ks) {
        acc = __builtin_amdgcn_mfma_f32_16x16x32_bf16(ahi[ks], whi[ks], acc, 0, 0, 0);
        acc = __builtin_amdgcn_mfma_f32_16x16x32_bf16(ahi[ks], wlo[ks], acc, 0, 0, 0);
        acc = __builtin_amdgcn_mfma_f32_16x16x32_bf16(alo[ks], whi[ks], acc, 0, 0, 0);
      }
      const int r0 = mt * 16 + ((lane >> 4) << 2);
      const float v0 = fmaxf(acc[0] + bias, 0.f);
      const float v1 = fmaxf(acc[1] + bias, 0.f);
      const float v2 = fmaxf(acc[2] + bias, 0.f);
      const float v3 = fmaxf(acc[3] + bias, 0.f);
      if (r0 / 20 == (r0 + 3) / 20) {
        atomicMax(&pm[r0 / 20][c], __float_as_uint(fmaxf(fmaxf(v0, v1), fmaxf(v2, v3))));
      } else {
        atomicMax(&pm[(r0 + 0) / 20][c], __float_as_uint(v0));
        atomicMax(&pm[(r0 + 1) / 20][c], __float_as_uint(v1));
        atomicMax(&pm[(r0 + 2) / 20][c], __float_as_uint(v2));
        atomicMax(&pm[(r0 + 3) / 20][c], __float_as_uint(v3));
      }
    }
  }
  __syncthreads();

  // ---- fused epilogue: x1 (fp32), split-bf16 xhi/xlo, s = sum(x^2)
  {
    const int p = t >> 5;                // group of 32 lanes per point
    const int cc = (t & 31) * 2;
    const size_t n = (size_t)(b * NN + pbase + p);
    float2 o;
    o.x = __uint_as_float(pm[p][cc]);
    o.y = __uint_as_float(pm[p][cc + 1]);
    *(float2*)&xout[n * 64 + cc] = o;
    // split bf16
    ushort2 hi, lo;
    hi.x = f2bf(o.x); lo.x = f2bf(o.x - bf2f(hi.x));
    hi.y = f2bf(o.y); lo.y = f2bf(o.y - bf2f(hi.y));
    *(ushort2*)&xhi[n * 64 + cc] = hi;
    *(ushort2*)&xlo[n * 64 + cc] = lo;
    // s: 32-lane shfl_xor tree (strides < 32 stay within the point's group)
    float ps = o.x * o.x + o.y * o.y;
    ps += __shfl_xor(ps, 1);
    ps += __shfl_xor(ps, 2);
    ps += __shfl_xor(ps, 4);
    ps += __shfl_xor(ps, 8);
    ps += __shfl_xor(ps, 16);
    if ((t & 31) == 0) sbuf[n] = ps;
  }
}

// ---------------------------------------------------------------------------
// d2 + fused partial selection (R10-proven 256-thread version, reverted).
// ---------------------------------------------------------------------------
__global__ __launch_bounds__(256) void d2sel_kernel(const unsigned short* __restrict__ xhi,
                                                    const unsigned short* __restrict__ xlo,
                                                    const float* __restrict__ s,
                                                    float* __restrict__ candd,
                                                    int* __restrict__ candi) {
  __shared__ __align__(16) unsigned short SBUF[4 * 128 * 72];
  __shared__ float sA[128], sB[128];
  float (*Tt)[132] = (float(*)[132])SBUF;
  const int bid = blockIdx.x;
  const int b = bid >> 8;
  const int tile = bid & 255;
  const int ti = tile >> 4, tj = tile & 15;
  const int i0 = ti * 128, j0 = tj * 128;
  const int gb = b * NN;
  const int t = threadIdx.x;
  const int wave = t >> 6, lane = t & 63;
  const int lrow = lane & 15;
  const int lk8 = (lane >> 4) * 8;

  for (int it = t; it < 4096; it += 256) {
    const int part = it >> 10;           // 0:AH 1:AL 2:BH 3:BL
    const int r = (it >> 3) & 127;
    const int g = it & 7;
    const unsigned short* src = (part == 0) ? xhi : (part == 1) ? xlo
                               : (part == 2) ? xhi : xlo;
    const int base = (part < 2) ? i0 : j0;
    *(uint4*)&SBUF[part * 9216 + r * 72 + g * 8] =
        *(const uint4*)&src[((size_t)(gb + base + r)) * 64 + g * 8];
  }
  if (t < 128) sA[t] = s[gb + i0 + t];
  else sB[t - 128] = s[gb + j0 + (t - 128)];
  __syncthreads();

  bf16x8 ahi[2][2], alo[2][2];
#pragma unroll
  for (int mt = 0; mt < 2; ++mt) {
    const int r = wave * 32 + mt * 16 + lrow;
#pragma unroll
    for (int ks = 0; ks < 2; ++ks) {
      ahi[mt][ks] = *(const bf16x8*)&SBUF[0 * 9216 + r * 72 + ks * 32 + lk8];
      alo[mt][ks] = *(const bf16x8*)&SBUF[1 * 9216 + r * 72 + ks * 32 + lk8];
    }
  }
  f32x4 acc[2][8];
#pragma unroll
  for (int mt = 0; mt < 2; ++mt)
#pragma unroll
    for (int nt = 0; nt < 8; ++nt) acc[mt][nt] = (f32x4){0.f, 0.f, 0.f, 0.f};
#pragma unroll
  for (int nt = 0; nt < 8; ++nt) {
    bf16x8 bhi[2], blo[2];
#pragma unroll
    for (int ks = 0; ks < 2; ++ks) {
      bhi[ks] = *(const bf16x8*)&SBUF[2 * 9216 + (nt * 16 + lrow) * 72 + ks * 32 + lk8];
      blo[ks] = *(const bf16x8*)&SBUF[3 * 9216 + (nt * 16 + lrow) * 72 + ks * 32 + lk8];
    }
#pragma unroll
    for (int mt = 0; mt < 2; ++mt) {
#pragma unroll
      for (int ks = 0; ks < 2; ++ks) {
        acc[mt][nt] = __builtin_amdgcn_mfma_f32_16x16x32_bf16(ahi[mt][ks], bhi[ks], acc[mt][nt], 0, 0, 0);
        acc[mt][nt] = __builtin_amdgcn_mfma_f32_16x16x32_bf16(ahi[mt][ks], blo[ks], acc[mt][nt], 0, 0, 0);
        acc[mt][nt] = __builtin_amdgcn_mfma_f32_16x16x32_bf16(alo[mt][ks], bhi[ks], acc[mt][nt], 0, 0, 0);
      }
    }
  }
  __syncthreads();   // all stage reads done before Tt overlays SBUF

#pragma unroll
  for (int mt = 0; mt < 2; ++mt) {
    const int ib = wave * 32 + mt * 16 + ((lane >> 4) << 2);
#pragma unroll
    for (int nt = 0; nt < 8; ++nt) {
      const int jj = nt * 16 + lrow;
      const float sj = sB[jj];
      float4 o;
      o.x = sA[ib + 0] + sj - 2.f * acc[mt][nt][0];
      o.y = sA[ib + 1] + sj - 2.f * acc[mt][nt][1];
      o.z = sA[ib + 2] + sj - 2.f * acc[mt][nt][2];
      o.w = sA[ib + 3] + sj - 2.f * acc[mt][nt][3];
      *(float4*)&Tt[jj][ib] = o;
    }
  }
  __syncthreads();

  const int j = t >> 1, h = t & 1;
  float sl[KK];
#pragma unroll
  for (int q = 0; q < KK; ++q) sl[q] = INFINITY;
  for (int r4 = 0; r4 < 16; ++r4) {
    const float4 v = *(const float4*)&Tt[j][h * 64 + r4 * 4];
    sins20(sl, v.x);
    sins20(sl, v.y);
    sins20(sl, v.z);
    sins20(sl, v.w);
  }
  {
    float od[KK];
#pragma unroll
    for (int q = 0; q < KK; ++q) od[q] = __shfl_xor(sl[q], 1);
#pragma unroll
    for (int q = 0; q < KK; ++q) sins20(sl, od[q]);
  }
  const float tau = sl[0];

  int cA = 0, cB = 0;
  for (int r4 = 0; r4 < 16; ++r4) {
    const float4 v = *(const float4*)&Tt[j][h * 64 + r4 * 4];
    cA += (v.x < tau) + (v.y < tau) + (v.z < tau) + (v.w < tau);
    cB += (v.x == tau) + (v.y == tau) + (v.z == tau) + (v.w == tau);
  }
  const int pA = __shfl_xor(cA, 1);
  const int pB = __shfl_xor(cB, 1);
  const int nA = cA + pA;
  int posA = h ? pA : 0;
  int posB = nA + (h ? pB : 0);

  const size_t obase = ((size_t)(b * 16 + ti) * KK) * 2048 + (j0 + j);
  for (int r4 = 0; r4 < 16; ++r4) {
    const float4 v = *(const float4*)&Tt[j][h * 64 + r4 * 4];
    const float dd[4] = {v.x, v.y, v.z, v.w};
#pragma unroll
    for (int u = 0; u < 4; ++u) {
      const float d = dd[u];
      const int row = i0 + h * 64 + r4 * 4 + u;
      if (d < tau) {
        candd[obase + (size_t)posA * 2048] = d;
        candi[obase + (size_t)posA * 2048] = row;
        ++posA;
      } else if (d == tau && posB < KK) {
        candd[obase + (size_t)posB * 2048] = d;
        candi[obase + (size_t)posB * 2048] = row;
        ++posB;
      }
    }
  }
}

// ---------------------------------------------------------------------------
// conv2 EdgeConv layers 2,3 via bf16 MFMA; in-place E; split-bf16 x2 out.
// ---------------------------------------------------------------------------
__global__ __launch_bounds__(256) void conv2_kernel(
    const float* __restrict__ U, const float* __restrict__ V,
    const int* __restrict__ idx,
    const unsigned short* __restrict__ w2t, const float* __restrict__ b2,
    const unsigned short* __restrict__ w3t, const float* __restrict__ b3,
    unsigned short* __restrict__ x2hi, unsigned short* __restrict__ x2lo) {
  __shared__ __align__(16) unsigned short E[80][136];
  __shared__ unsigned int pm[4][256];
  const int bid = blockIdx.x;
  const int b = bid >> 9;
  const int pbase = (bid & 511) * 4;
  const int t = threadIdx.x;
  const int wave = t >> 6, lane = t & 63;
  const int lrow = lane & 15;
  const int lk8 = (lane >> 4) * 8;

  for (int it = t; it < 2560; it += 256) {
    const int r = it >> 5, q = it & 31;
    const int p = r / 20, k = r - (r / 20) * 20;
    const int n = b * NN + pbase + p;
    const int j = b * NN + idx[(size_t)n * KK + k];
    const float4 uv = *(const float4*)&U[(size_t)n * 128 + q * 4];
    const float4 vv = *(const float4*)&V[(size_t)j * 128 + q * 4];
    ushort4 h;
    h.x = f2bf(fmaxf(uv.x + vv.x, 0.f));
    h.y = f2bf(fmaxf(uv.y + vv.y, 0.f));
    h.z = f2bf(fmaxf(uv.z + vv.z, 0.f));
    h.w = f2bf(fmaxf(uv.w + vv.w, 0.f));
    *(ushort4*)&E[r][q * 4] = h;
  }
  for (int i = t; i < 1024; i += 256) ((unsigned int*)pm)[i] = 0u;
  __syncthreads();

  // ---- layer 2: [80x128] @ [128x128], in-place (accs reg-buffered)
  {
    bf16x8 wf[2][4];
#pragma unroll
    for (int nt2 = 0; nt2 < 2; ++nt2) {
      const int ntg = wave * 2 + nt2;
#pragma unroll
      for (int ks = 0; ks < 4; ++ks)
        wf[nt2][ks] = *(const bf16x8*)&w2t[(size_t)(ntg * 16 + lrow) * 128 + ks * 32 + lk8];
    }
    f32x4 a0buf[5], a1buf[5];
#pragma unroll
    for (int mt = 0; mt < 5; ++mt) {
      bf16x8 af[4];
#pragma unroll
      for (int ks = 0; ks < 4; ++ks)
        af[ks] = *(const bf16x8*)&E[mt * 16 + lrow][ks * 32 + lk8];
      f32x4 acc0 = {0.f, 0.f, 0.f, 0.f};
      f32x4 acc1 = {0.f, 0.f, 0.f, 0.f};
#pragma unroll
      for (int ks = 0; ks < 4; ++ks) {
        acc0 = __builtin_amdgcn_mfma_f32_16x16x32_bf16(af[ks], wf[0][ks], acc0, 0, 0, 0);
        acc1 = __builtin_amdgcn_mfma_f32_16x16x32_bf16(af[ks], wf[1][ks], acc1, 0, 0, 0);
      }
      a0buf[mt] = acc0;
      a1buf[mt] = acc1;
    }
    __syncthreads();   // all layer-2 E reads done before overwrite
    const float bias0 = b2[wave * 32 + lrow];
    const float bias1 = b2[wave * 32 + 16 + lrow];
#pragma unroll
    for (int mt = 0; mt < 5; ++mt) {
      const int r0 = mt * 16 + ((lane >> 4) << 2);
      const int c0 = wave * 32 + lrow;
#pragma unroll
      for (int reg = 0; reg < 4; ++reg) {
        E[r0 + reg][c0]      = f2bf(fmaxf(a0buf[mt][reg] + bias0, 0.f));
        E[r0 + reg][c0 + 16] = f2bf(fmaxf(a1buf[mt][reg] + bias1, 0.f));
      }
    }
  }
  __syncthreads();

  // ---- layer 3: [80x128] @ [128x256], relu+bias, max over edges into pm
  {
    bf16x8 wf[4][4];
#pragma unroll
    for (int nt4 = 0; nt4 < 4; ++nt4) {
      const int ntg = wave * 4 + nt4;
#pragma unroll
      for (int ks = 0; ks < 4; ++ks)
        wf[nt4][ks] = *(const bf16x8*)&w3t[(size_t)(ntg * 16 + lrow) * 128 + ks * 32 + lk8];
    }
#pragma unroll
    for (int mt = 0; mt < 5; ++mt) {
      bf16x8 af[4];
#pragma unroll
      for (int ks = 0; ks < 4; ++ks)
        af[ks] = *(const bf16x8*)&E[mt * 16 + lrow][ks * 32 + lk8];
      f32x4 acc[4];
#pragma unroll
      for (int nt4 = 0; nt4 < 4; ++nt4) acc[nt4] = (f32x4){0.f, 0.f, 0.f, 0.f};
#pragma unroll
      for (int ks = 0; ks < 4; ++ks) {
#pragma unroll
        for (int nt4 = 0; nt4 < 4; ++nt4)
          acc[nt4] = __builtin_amdgcn_mfma_f32_16x16x32_bf16(af[ks], wf[nt4][ks], acc[nt4], 0, 0, 0);
      }
      const int r0 = mt * 16 + ((lane >> 4) << 2);
      const int pa = r0 / 20;
      const int pb = (r0 + 3) / 20;
#pragma unroll
      for (int nt4 = 0; nt4 < 4; ++nt4) {
        const int c = wave * 64 + nt4 * 16 + lrow;
        const float bias = b3[c];
        float v0 = fmaxf(acc[nt4][0] + bias, 0.f);
        float v1 = fmaxf(acc[nt4][1] + bias, 0.f);
        float v2 = fmaxf(acc[nt4][2] + bias, 0.f);
        float v3 = fmaxf(acc[nt4][3] + bias, 0.f);
        if (pa == pb) {
          atomicMax(&pm[pa][c], __float_as_uint(fmaxf(fmaxf(v0, v1), fmaxf(v2, v3))));
        } else {
          atomicMax(&pm[(r0 + 0) / 20][c], __float_as_uint(v0));
          atomicMax(&pm[(r0 + 1) / 20][c], __float_as_uint(v1));
          atomicMax(&pm[(r0 + 2) / 20][c], __float_as_uint(v2));
          atomicMax(&pm[(r0 + 3) / 20][c], __float_as_uint(v3));
        }
      }
    }
  }
  __syncthreads();

  // ---- write split-bf16 x2 (values >= 0)
  {
    const int p = t >> 6;
    const int c0 = (t & 63) * 4;
    const float4 o = *(const float4*)&pm[p][c0];
    ushort4 hi, lo;
    hi.x = f2bf(o.x); lo.x = f2bf(o.x - bf2f(hi.x));
    hi.y = f2bf(o.y); lo.y = f2bf(o.y - bf2f(hi.y));
    hi.z = f2bf(o.z); lo.z = f2bf(o.z - bf2f(hi.z));
    hi.w = f2bf(o.w); lo.w = f2bf(o.w - bf2f(hi.w));
    const size_t base = ((size_t)b * NN + pbase + p) * 256 + c0;
    *(ushort4*)&x2hi[base] = hi;
    *(ushort4*)&x2lo[base] = lo;
  }
}

// ---------------------------------------------------------------------------
// l0 via split-bf16 MFMA (unchanged, proven R10).
// ---------------------------------------------------------------------------
__global__ __launch_bounds__(256) void l0_kernel(
    const unsigned short* __restrict__ x2hi, const unsigned short* __restrict__ x2lo,
    const unsigned short* __restrict__ l0thi, const unsigned short* __restrict__ l0tlo,
    const float* __restrict__ bias, float* __restrict__ gp) {
  __shared__ __align__(16) unsigned short Ahi[64][72];
  __shared__ __align__(16) unsigned short Alo[64][72];
  __shared__ unsigned int pm[256];
  const int bid = blockIdx.x;
  const int cblk = bid & 1;
  const int mblk = (bid >> 1) & 31;
  const int b = bid >> 6;
  const int t = threadIdx.x;
  const int wave = t >> 6, lane = t & 63;
  const int lrow = lane & 15;
  const int lk8 = (lane >> 4) * 8;
  const size_t rowbase = (size_t)(b * NN + mblk * 64);
  const int cbase = cblk * 256;

  pm[t] = 0u;

  f32x4 acc[4][4];
#pragma unroll
  for (int mt = 0; mt < 4; ++mt)
#pragma unroll
    for (int nt = 0; nt < 4; ++nt) acc[mt][nt] = (f32x4){0.f, 0.f, 0.f, 0.f};

  for (int kc = 0; kc < 4; ++kc) {
    for (int it = t; it < 1024; it += 256) {
      const int buf = it >> 9;
      const int r = (it >> 3) & 63;
      const int g = it & 7;
      const unsigned short* src = buf ? x2lo : x2hi;
      const uint4 v = *(const uint4*)&src[(rowbase + r) * 256 + kc * 64 + g * 8];
      if (buf) *(uint4*)&Alo[r][g * 8] = v;
      else     *(uint4*)&Ahi[r][g * 8] = v;
    }
    __syncthreads();

    bf16x8 bhi[4][2], blo[4][2];
#pragma unroll
    for (int nt = 0; nt < 4; ++nt) {
      const size_t c = (size_t)(cbase + wave * 64 + nt * 16 + lrow);
#pragma unroll
      for (int ks = 0; ks < 2; ++ks) {
        bhi[nt][ks] = *(const bf16x8*)&l0thi[c * 256 + kc * 64 + ks * 32 + lk8];
        blo[nt][ks] = *(const bf16x8*)&l0tlo[c * 256 + kc * 64 + ks * 32 + lk8];
      }
    }
#pragma unroll
    for (int mt = 0; mt < 4; ++mt) {
      bf16x8 ahi[2], alo[2];
#pragma unroll
      for (int ks = 0; ks < 2; ++ks) {
        ahi[ks] = *(const bf16x8*)&Ahi[mt * 16 + lrow][ks * 32 + lk8];
        alo[ks] = *(const bf16x8*)&Alo[mt * 16 + lrow][ks * 32 + lk8];
      }
#pragma unroll
      for (int nt = 0; nt < 4; ++nt) {
#pragma unroll
        for (int ks = 0; ks < 2; ++ks) {
          acc[mt][nt] = __builtin_amdgcn_mfma_f32_16x16x32_bf16(ahi[ks], bhi[nt][ks], acc[mt][nt], 0, 0, 0);
          acc[mt][nt] = __builtin_amdgcn_mfma_f32_16x16x32_bf16(ahi[ks], blo[nt][ks], acc[mt][nt], 0, 0, 0);
          acc[mt][nt] = __builtin_amdgcn_mfma_f32_16x16x32_bf16(alo[ks], bhi[nt][ks], acc[mt][nt], 0, 0, 0);
        }
      }
    }
    __syncthreads();
  }

#pragma unroll
  for (int nt = 0; nt < 4; ++nt) {
    const int cl = wave * 64 + nt * 16 + lrow;
    const float bv = bias[cbase + cl];
    float mx = 0.f;
#pragma unroll
    for (int mt = 0; mt < 4; ++mt)
#pragma unroll
      for (int reg = 0; reg < 4; ++reg)
        mx = fmaxf(mx, fmaxf(acc[mt][nt][reg] + bv, 0.f));
    atomicMax(&pm[cl], __float_as_uint(mx));
  }
  __syncthreads();
  gp[((size_t)(b * 32 + mblk)) * 512 + cbase + t] = __uint_as_float(pm[t]);
}

// ---------------------------------------------------------------------------
// final pool-reduce (32 partials) + classifier head + log_softmax (unchanged).
// ---------------------------------------------------------------------------
__global__ __launch_bounds__(256) void head_kernel(
    const float* __restrict__ gp,
    const float* __restrict__ l1w, const float* __restrict__ l1b,
    const float* __restrict__ l2w, const float* __restrict__ l2b,
    const float* __restrict__ l3w, const float* __restrict__ l3b,
    float* __restrict__ out) {
  __shared__ float g[512];
  __shared__ float h1[256];
  __shared__ float h2[256];
  __shared__ float logits[40];
  __shared__ float lse_s;
  const int b = blockIdx.x;
  const int t = threadIdx.x;
  for (int cidx = t; cidx < 512; cidx += 256) {
    float m = gp[(size_t)(b * 32) * 512 + cidx];
    for (int ch = 1; ch < 32; ++ch) m = fmaxf(m, gp[(size_t)(b * 32 + ch) * 512 + cidx]);
    g[cidx] = m;
  }
  __syncthreads();
  {
    float acc = 0.f;
    for (int d = 0; d < 512; d += 4) {
      const float4 gv = *(const float4*)&g[d];
      acc = fmaf(gv.x, l1w[(size_t)d * 256 + t], acc);
      acc = fmaf(gv.y, l1w[(size_t)(d + 1) * 256 + t], acc);
      acc = fmaf(gv.z, l1w[(size_t)(d + 2) * 256 + t], acc);
      acc = fmaf(gv.w, l1w[(size_t)(d + 3) * 256 + t], acc);
    }
    h1[t] = fmaxf(acc + l1b[t], 0.f);
  }
  __syncthreads();
  {
    float acc = 0.f;
    for (int d = 0; d < 256; d += 4) {
      const float4 hv = *(const float4*)&h1[d];
      acc = fmaf(hv.x, l2w[(size_t)d * 256 + t], acc);
      acc = fmaf(hv.y, l2w[(size_t)(d + 1) * 256 + t], acc);
      acc = fmaf(hv.z, l2w[(size_t)(d + 2) * 256 + t], acc);
      acc = fmaf(hv.w, l2w[(size_t)(d + 3) * 256 + t], acc);
    }
    h2[t] = fmaxf(acc + l2b[t], 0.f);
  }
  __syncthreads();
  if (t < 40) {
    float acc = 0.f;
    for (int d = 0; d < 256; ++d) acc = fmaf(h2[d], l3w[(size_t)d * 40 + t], acc);
    logits[t] = acc + l3b[t];
  }
  __syncthreads();
  if (t == 0) {
    float M = -INFINITY;
    for (int j = 0; j < 40; ++j) M = fmaxf(M, logits[j]);
    float ssum = 0.f;
    for (int j = 0; j < 40; ++j) ssum += expf(logits[j] - M);
    lse_s = M + logf(ssum);
  }
  __syncthreads();
  if (t < 40) out[(size_t)b * 40 + t] = logits[t] - lse_s;
}

// ---------------------------------------------------------------------------
extern "C" void kernel_launch(void* const* d_in, const int* in_sizes, int n_in,
                              void* d_out, int out_size, void* d_ws, size_t ws_size,
                              hipStream_t stream) {
  const float* pos  = (const float*)d_in[0];
  const float* c1w1 = (const float*)d_in[2];
  const float* c1b1 = (const float*)d_in[3];
  const float* c1w2 = (const float*)d_in[4];
  const float* c1b2 = (const float*)d_in[5];
  const float* c1w3 = (const float*)d_in[6];
  const float* c1b3 = (const float*)d_in[7];
  const float* c2w1 = (const float*)d_in[8];
  const float* c2b1 = (const float*)d_in[9];
  const float* c2w2 = (const float*)d_in[10];
  const float* c2b2 = (const float*)d_in[11];
  const float* c2w3 = (const float*)d_in[12];
  const float* c2b3 = (const float*)d_in[13];
  const float* l0w  = (const float*)d_in[14];
  const float* l0b  = (const float*)d_in[15];
  const float* l1w  = (const float*)d_in[16];
  const float* l1b  = (const float*)d_in[17];
  const float* l2w  = (const float*)d_in[18];
  const float* l2b  = (const float*)d_in[19];
  const float* l3w  = (const float*)d_in[20];
  const float* l3b  = (const float*)d_in[21];
  float* out = (float*)d_out;

  char* ws = (char*)d_ws;
  float* x1    = (float*)(ws + 0);                      // 4 MB    [8,2048,64]
  int*   idx1  = (int*)  (ws + ((size_t)20 << 20));     // 1.31 MB [16384,20]
  int*   idx2  = (int*)  (ws + ((size_t)22 << 20));     // 1.31 MB
  float* gp    = (float*)(ws + ((size_t)24 << 20));     // 512 KB  [8,32,512]
  unsigned short* w2t    = (unsigned short*)(ws + ((size_t)24 << 20) + (512 << 10)); // 32 KB
  unsigned short* w3t    = (unsigned short*)(ws + ((size_t)24 << 20) + (544 << 10)); // 64 KB
  unsigned short* c1w2hi = (unsigned short*)(ws + ((size_t)24 << 20) + (608 << 10)); // 8 KB
  unsigned short* c1w2lo = (unsigned short*)(ws + ((size_t)24 << 20) + (616 << 10)); // 8 KB
  unsigned short* c1w3hi = (unsigned short*)(ws + ((size_t)24 << 20) + (624 << 10)); // 8 KB
  unsigned short* c1w3lo = (unsigned short*)(ws + ((size_t)24 << 20) + (632 << 10)); // 8 KB
  float* candd = (float*)(ws + ((size_t)25 << 20));     // 21 MB   [8,16,20,2048]
  int*   candi = (int*)  (ws + ((size_t)46 << 20));     // 21 MB (ends 67 MB)
  // Overlays (regions dead at time of use):
  float* U1 = (float*)(ws + ((size_t)25 << 20));        // 4 MB over candd (dead after merge1)
  float* V1 = (float*)(ws + ((size_t)29 << 20));        // 4 MB
  float* U  = (float*)(ws + ((size_t)46 << 20));        // 8 MB over candi (dead after merge2)
  float* Vv = (float*)(ws + ((size_t)54 << 20));        // 8 MB (ends at 62 MB)
  // Non-overlapping tail:
  unsigned short* xhi  = (unsigned short*)(ws + ((size_t)68 << 20));  // 2 MB
  unsigned short* xlo  = (unsigned short*)(ws + ((size_t)70 << 20));  // 2 MB
  float*          sbuf = (float*)         (ws + ((size_t)72 << 20));  // 64 KB
  unsigned short* x2hi = (unsigned short*)(ws + ((size_t)73 << 20));  // 8 MB
  unsigned short* x2lo = (unsigned short*)(ws + ((size_t)81 << 20));  // 8 MB
  unsigned short* l0thi = (unsigned short*)(ws + ((size_t)89 << 20));            // 256 KB
  unsigned short* l0tlo = (unsigned short*)(ws + ((size_t)89 << 20) + (256 << 10)); // 256 KB

  wprep_kernel<<<736, 256, 0, stream>>>(c2w2, c2w3, c1w2, c1w3, l0w,
                                        w2t, w3t, c1w2hi, c1w2lo, c1w3hi, c1w3lo,
                                        l0thi, l0tlo);
  knn1_part<<<512, 256, 0, stream>>>(pos, candd, candi);
  merge_topk2<8, 4><<<256, 256, 0, stream>>>(candd, candi, idx1);
  pre1_kernel<<<4096, 256, 0, stream>>>(pos, c1w1, c1b1, U1, V1);      // overwrites candd region
  conv1_kernel<<<2048, 256, 0, stream>>>(U1, V1, idx1, c1w2hi, c1w2lo, c1b2,
                                         c1w3hi, c1w3lo, c1b3, x1, xhi, xlo, sbuf);
  d2sel_kernel<<<2048, 256, 0, stream>>>(xhi, xlo, sbuf, candd, candi); // U1/V1 dead now
  merge_topk2<16, 8><<<512, 256, 0, stream>>>(candd, candi, idx2);
  pre2_kernel<<<256, 256, 0, stream>>>(x1, c2w1, c2b1, U, Vv);         // overwrites candi region
  conv2_kernel<<<4096, 256, 0, stream>>>(U, Vv, idx2, w2t, c2b2, w3t, c2b3, x2hi, x2lo);
  l0_kernel<<<512, 256, 0, stream>>>(x2hi, x2lo, l0thi, l0tlo, l0b, gp);
  head_kernel<<<8, 256, 0, stream>>>(gp, l1w, l1b, l2w, l2b, l3w, l3b, out);
}